// Round 1
// baseline (3064.346 us; speedup 1.0000x reference)
//
#include <hip/hip_runtime.h>
#include <math.h>

// GAT 2-layer: N=50000 nodes, E=800000 edges, heads=1
// dims: 128 -> 128 (BN+ReLU) -> 112 (BN)
#define NN 50000
#define NE 800000
constexpr int K_DIM = 128;

__device__ __forceinline__ unsigned encF(float x) {
    unsigned u = __float_as_uint(x);
    return (u & 0x80000000u) ? ~u : (u | 0x80000000u);
}
__device__ __forceinline__ float decF(unsigned u) {
    return __uint_as_float((u & 0x80000000u) ? (u ^ 0x80000000u) : ~u);
}

// ---------------- init ----------------
__global__ void k_init(float* h, unsigned* m0, float* den0, unsigned* m1, float* den1,
                       float* stats, int hsize, int n, int ssize)
{
    int idx = blockIdx.x * blockDim.x + threadIdx.x;
    if (idx < hsize) h[idx] = 0.f;
    if (idx < n) {
        m0[idx] = 0x007FFFFFu;   // enc(-inf)
        m1[idx] = 0x007FFFFFu;
        den0[idx] = 0.f;
        den1[idx] = 0.f;
    }
    if (idx < ssize) stats[idx] = 0.f;
}

__global__ void k_zero(float* p, int nvals)
{
    int idx = blockIdx.x * blockDim.x + threadIdx.x;
    if (idx < nvals) p[idx] = 0.f;
}

// ve[0..7] = We0 @ a_edge0 ; ve[8..15] = We1 @ a_edge1   (heads=1 folding)
__global__ void k_ve(const float* We0, const float* ae0, const float* We1, const float* ae1,
                     float* ve)
{
    int j = threadIdx.x;
    if (j < 8) {
        float s = 0.f;
        for (int c = 0; c < 128; ++c) s += We0[j*128 + c] * ae0[c];
        ve[j] = s;
    } else if (j < 16) {
        int jj = j - 8;
        float s = 0.f;
        for (int c = 0; c < 112; ++c) s += We1[jj*112 + c] * ae1[c];
        ve[8 + jj] = s;
    }
}

// ---------------- node GEMM: out[r,c] = sum_k A[r,k]*W[k,c], K=128 ----------------
template<int COLS>
__global__ void k_gemm(const float* __restrict__ A, const float* __restrict__ W,
                       float* __restrict__ out, int nrows)
{
    __shared__ float Xl[8 * K_DIM];     // 8 rows of A
    int c = threadIdx.x & 127;
    int g = threadIdx.x >> 7;           // 0..1 -> rows g*4 .. g*4+3
    for (int rb = blockIdx.x * 8; rb < nrows; rb += gridDim.x * 8) {
        __syncthreads();
        for (int i = threadIdx.x; i < 8 * K_DIM; i += blockDim.x) {
            int r = rb + (i >> 7);
            Xl[i] = (r < nrows) ? A[(size_t)r * K_DIM + (i & 127)] : 0.f;
        }
        __syncthreads();
        if (c < COLS) {
            float acc0 = 0.f, acc1 = 0.f, acc2 = 0.f, acc3 = 0.f;
            const float* xb = &Xl[g * 4 * K_DIM];
            #pragma unroll 8
            for (int k = 0; k < K_DIM; ++k) {
                float w = W[k * COLS + c];
                acc0 += xb[0 * K_DIM + k] * w;
                acc1 += xb[1 * K_DIM + k] * w;
                acc2 += xb[2 * K_DIM + k] * w;
                acc3 += xb[3 * K_DIM + k] * w;
            }
            int r0 = rb + g * 4;
            if (r0 + 0 < nrows) out[(size_t)(r0 + 0) * COLS + c] = acc0;
            if (r0 + 1 < nrows) out[(size_t)(r0 + 1) * COLS + c] = acc1;
            if (r0 + 2 < nrows) out[(size_t)(r0 + 2) * COLS + c] = acc2;
            if (r0 + 3 < nrows) out[(size_t)(r0 + 3) * COLS + c] = acc3;
        }
    }
}

// ---------------- per-node attention dots: one wave per row ----------------
template<int COLS>
__global__ void k_node_al(const float* __restrict__ xs, const float* __restrict__ a_src,
                          const float* __restrict__ a_dst,
                          float* __restrict__ al_src, float* __restrict__ al_dst, int n)
{
    int w = (blockIdx.x * blockDim.x + threadIdx.x) >> 6;
    int lane = threadIdx.x & 63;
    if (w >= n) return;
    const float* row = xs + (size_t)w * COLS;
    float s = 0.f, d = 0.f;
    #pragma unroll
    for (int c0 = 0; c0 < COLS; c0 += 64) {
        int c = c0 + lane;
        if (c < COLS) {
            float v = row[c];
            s += v * a_src[c];
            d += v * a_dst[c];
        }
    }
    #pragma unroll
    for (int off = 32; off > 0; off >>= 1) {
        s += __shfl_down(s, off);
        d += __shfl_down(d, off);
    }
    if (lane == 0) { al_src[w] = s; al_dst[w] = d; }
}

// ---------------- edge: alpha + segment max ----------------
__global__ void k_edge_alpha(const int* __restrict__ src, const int* __restrict__ dst,
                             const float* __restrict__ eatt, const float* __restrict__ ve,
                             const float* __restrict__ al_src, const float* __restrict__ al_dst,
                             float* __restrict__ ealpha, unsigned* __restrict__ m, int E_)
{
    int e = blockIdx.x * blockDim.x + threadIdx.x;
    if (e >= E_) return;
    const float4* ea = reinterpret_cast<const float4*>(eatt + (size_t)e * 8);
    float4 e0 = ea[0], e1 = ea[1];
    float ae = e0.x * ve[0] + e0.y * ve[1] + e0.z * ve[2] + e0.w * ve[3]
             + e1.x * ve[4] + e1.y * ve[5] + e1.z * ve[6] + e1.w * ve[7];
    int d = dst[e];
    float a = al_src[src[e]] + al_dst[d] + ae;
    a = a > 0.f ? a : 0.2f * a;       // leaky_relu(0.2)
    ealpha[e] = a;
    atomicMax(&m[d], encF(a));
}

// ---------------- edge: exp + denominator ----------------
__global__ void k_edge_exp(const int* __restrict__ dst, float* __restrict__ ealpha,
                           const unsigned* __restrict__ m, float* __restrict__ den, int E_)
{
    int e = blockIdx.x * blockDim.x + threadIdx.x;
    if (e >= E_) return;
    int d = dst[e];
    float ex = __expf(ealpha[e] - decF(m[d]));
    ealpha[e] = ex;
    unsafeAtomicAdd(&den[d], ex);
}

// ---------------- edge: gather * att -> scatter-add ----------------
template<int COLS>
__global__ void k_scatter(const int* __restrict__ src, const int* __restrict__ dst,
                          const float* __restrict__ ex, const float* __restrict__ den,
                          const float* __restrict__ xs, float* __restrict__ out, int E_)
{
    int idx = blockIdx.x * blockDim.x + threadIdx.x;
    int e = idx >> 5;                 // 32 threads / edge, float4 each
    int c4 = idx & 31;
    if (e >= E_) return;
    constexpr int NC4 = COLS / 4;
    if (c4 >= NC4) return;
    int s = src[e], d = dst[e];
    float att = ex[e] / den[d];
    float4 v = reinterpret_cast<const float4*>(xs + (size_t)s * COLS)[c4];
    float* op = out + (size_t)d * COLS + c4 * 4;
    unsafeAtomicAdd(op + 0, v.x * att);
    unsafeAtomicAdd(op + 1, v.y * att);
    unsafeAtomicAdd(op + 2, v.z * att);
    unsafeAtomicAdd(op + 3, v.w * att);
}

// ---------------- batchnorm stats ----------------
template<int COLS>
__global__ void k_bn_stats(const float* __restrict__ h, float* __restrict__ sums,
                           float* __restrict__ sqs, int n)
{
    int c = threadIdx.x & 127;
    int g = threadIdx.x >> 7;
    if (c >= COLS) return;
    float s = 0.f, q = 0.f;
    for (int r = blockIdx.x * 2 + g; r < n; r += gridDim.x * 2) {
        float v = h[(size_t)r * COLS + c];
        s += v; q += v * v;
    }
    unsafeAtomicAdd(&sums[c], s);
    unsafeAtomicAdd(&sqs[c], q);
}

// ---------------- batchnorm apply (+ optional relu) ----------------
template<int COLS, bool RELU>
__global__ void k_bn_apply(const float* __restrict__ in, float* __restrict__ out,
                           const float* __restrict__ sums, const float* __restrict__ sqs,
                           const float* __restrict__ gamma, const float* __restrict__ beta,
                           int n)
{
    int idx = blockIdx.x * blockDim.x + threadIdx.x;
    if (idx >= n * COLS) return;
    int c = idx % COLS;
    float invn = 1.0f / (float)n;
    float mean = sums[c] * invn;
    float var  = sqs[c] * invn - mean * mean;     // biased, matches jnp var
    float sc = gamma[c] * rsqrtf(var + 1e-5f);
    float sh = beta[c] - mean * sc;
    float v = in[idx] * sc + sh;
    if (RELU) v = fmaxf(v, 0.f);
    out[idx] = v;
}

extern "C" void kernel_launch(void* const* d_in, const int* in_sizes, int n_in,
                              void* d_out, int out_size, void* d_ws, size_t ws_size,
                              hipStream_t stream)
{
    const float* x    = (const float*)d_in[0];
    const int*   eidx = (const int*)d_in[1];
    const float* eatt = (const float*)d_in[2];
    const float* W0   = (const float*)d_in[3];
    const float* as0  = (const float*)d_in[4];
    const float* ad0  = (const float*)d_in[5];
    const float* We0  = (const float*)d_in[6];
    const float* ae0  = (const float*)d_in[7];
    // d_in[8] = b0 : cancels through BN
    const float* W1   = (const float*)d_in[9];
    const float* as1  = (const float*)d_in[10];
    const float* ad1  = (const float*)d_in[11];
    const float* We1  = (const float*)d_in[12];
    const float* ae1  = (const float*)d_in[13];
    // d_in[14] = b1 : cancels through BN
    const float* bng  = (const float*)d_in[15];
    const float* bnb  = (const float*)d_in[16];
    const float* bnfg = (const float*)d_in[17];
    const float* bnfb = (const float*)d_in[18];

    const int N = NN, E = NE;
    const int* src = eidx;
    const int* dst = eidx + E;

    float* ws = (float*)d_ws;
    size_t off = 0;
    float* xs0 = ws + off;      off += (size_t)N * 128;
    float* h   = ws + off;      off += (size_t)N * 128;
    float* xs1 = ws + off;      off += (size_t)N * 112;
    float* ealpha = ws + off;   off += E;
    float* al_s0 = ws + off;    off += N;
    float* al_d0 = ws + off;    off += N;
    unsigned* m0 = (unsigned*)(ws + off); off += N;
    float* den0 = ws + off;     off += N;
    float* al_s1 = ws + off;    off += N;
    float* al_d1 = ws + off;    off += N;
    unsigned* m1 = (unsigned*)(ws + off); off += N;
    float* den1 = ws + off;     off += N;
    float* stats = ws + off;    off += 512;
    float* ve = ws + off;       off += 16;
    float* out1 = xs0;          // alias: xs0 is dead after layer-0 scatter

    float* sum0 = stats;
    float* sq0  = stats + 128;
    float* sum1 = stats + 256;
    float* sq1  = stats + 368;

    // ---- init (ws is poisoned 0xAA before every call) ----
    k_init<<<(N * 128 + 255) / 256, 256, 0, stream>>>(h, m0, den0, m1, den1, stats, N * 128, N, 512);
    k_ve<<<1, 64, 0, stream>>>(We0, ae0, We1, ae1, ve);

    // ---- layer 0: 128 -> 128 ----
    k_gemm<128><<<2048, 256, 0, stream>>>(x, W0, xs0, N);
    k_node_al<128><<<(N * 64 + 255) / 256, 256, 0, stream>>>(xs0, as0, ad0, al_s0, al_d0, N);
    k_edge_alpha<<<(E + 255) / 256, 256, 0, stream>>>(src, dst, eatt, ve, al_s0, al_d0, ealpha, m0, E);
    k_edge_exp<<<(E + 255) / 256, 256, 0, stream>>>(dst, ealpha, m0, den0, E);
    k_scatter<128><<<(E * 32 + 255) / 256, 256, 0, stream>>>(src, dst, ealpha, den0, xs0, h, E);
    k_bn_stats<128><<<1024, 256, 0, stream>>>(h, sum0, sq0, N);
    k_bn_apply<128, true><<<(N * 128 + 255) / 256, 256, 0, stream>>>(h, h, sum0, sq0, bng, bnb, N);

    // zero layer-1 accumulator (aliases xs0; must run after layer-0 scatter)
    k_zero<<<(N * 112 + 255) / 256, 256, 0, stream>>>(out1, N * 112);

    // ---- layer 1: 128 -> 112 ----
    k_gemm<112><<<2048, 256, 0, stream>>>(h, W1, xs1, N);
    k_node_al<112><<<(N * 64 + 255) / 256, 256, 0, stream>>>(xs1, as1, ad1, al_s1, al_d1, N);
    k_edge_alpha<<<(E + 255) / 256, 256, 0, stream>>>(src, dst, eatt, ve + 8, al_s1, al_d1, ealpha, m1, E);
    k_edge_exp<<<(E + 255) / 256, 256, 0, stream>>>(dst, ealpha, m1, den1, E);
    k_scatter<112><<<(E * 32 + 255) / 256, 256, 0, stream>>>(src, dst, ealpha, den1, xs1, out1, E);
    k_bn_stats<112><<<1024, 256, 0, stream>>>(out1, sum1, sq1, N);
    k_bn_apply<112, false><<<(N * 112 + 255) / 256, 256, 0, stream>>>(out1, (float*)d_out, sum1, sq1, bnfg, bnfb, N);
}

// Round 2
// 851.529 us; speedup vs baseline: 3.5986x; 3.5986x over previous
//
#include <hip/hip_runtime.h>
#include <math.h>

// GAT 2-layer: N=50000 nodes, E=800000 edges, heads=1
// dims: 128 -> 128 (BN+ReLU) -> 112 (BN)
#define NN 50000
#define NE 800000
constexpr int K_DIM = 128;

// ---------------- init ----------------
__global__ void k_init(int* deg, float* stats, int n, int ssize)
{
    int idx = blockIdx.x * blockDim.x + threadIdx.x;
    if (idx < n) deg[idx] = 0;
    if (idx < ssize) stats[idx] = 0.f;
}

// ve[0..7] = We0 @ a_edge0 ; ve[8..15] = We1 @ a_edge1   (heads=1 folding)
__global__ void k_ve(const float* We0, const float* ae0, const float* We1, const float* ae1,
                     float* ve)
{
    int j = threadIdx.x;
    if (j < 8) {
        float s = 0.f;
        for (int c = 0; c < 128; ++c) s += We0[j*128 + c] * ae0[c];
        ve[j] = s;
    } else if (j < 16) {
        int jj = j - 8;
        float s = 0.f;
        for (int c = 0; c < 112; ++c) s += We1[jj*112 + c] * ae1[c];
        ve[8 + jj] = s;
    }
}

// ---------------- CSR build ----------------
__global__ void k_deg(const int* __restrict__ dst, int* __restrict__ deg, int E_)
{
    int e = blockIdx.x * blockDim.x + threadIdx.x;
    if (e < E_) atomicAdd(&deg[dst[e]], 1);
}

// single-block exclusive scan of deg[0..NN) -> rp, and two cursor copies
__global__ void k_scan(const int* __restrict__ deg, int* __restrict__ rp,
                       int* __restrict__ cur0, int* __restrict__ cur1)
{
    __shared__ int part[1024];
    const int CH = (NN + 1023) / 1024;   // 49
    int t = threadIdx.x;
    int begin = t * CH;
    int s = 0;
    for (int i = 0; i < CH; ++i) {
        int idx = begin + i;
        if (idx < NN) s += deg[idx];
    }
    part[t] = s;
    __syncthreads();
    for (int off = 1; off < 1024; off <<= 1) {
        int v = (t >= off) ? part[t - off] : 0;
        __syncthreads();
        part[t] += v;
        __syncthreads();
    }
    int run = (t == 0) ? 0 : part[t - 1];
    for (int i = 0; i < CH; ++i) {
        int idx = begin + i;
        if (idx < NN) {
            rp[idx] = run; cur0[idx] = run; cur1[idx] = run;
            run += deg[idx];
        }
    }
    if (t == 1023) rp[NN] = part[1023];
}

// ---------------- node GEMM: out[r,c] = sum_k A[r,k]*W[k,c], K=128 ----------------
template<int COLS>
__global__ void k_gemm(const float* __restrict__ A, const float* __restrict__ W,
                       float* __restrict__ out, int nrows)
{
    __shared__ float Xl[8 * K_DIM];     // 8 rows of A
    int c = threadIdx.x & 127;
    int g = threadIdx.x >> 7;           // 0..1 -> rows g*4 .. g*4+3
    for (int rb = blockIdx.x * 8; rb < nrows; rb += gridDim.x * 8) {
        __syncthreads();
        for (int i = threadIdx.x; i < 8 * K_DIM; i += blockDim.x) {
            int r = rb + (i >> 7);
            Xl[i] = (r < nrows) ? A[(size_t)r * K_DIM + (i & 127)] : 0.f;
        }
        __syncthreads();
        if (c < COLS) {
            float acc0 = 0.f, acc1 = 0.f, acc2 = 0.f, acc3 = 0.f;
            const float* xb = &Xl[g * 4 * K_DIM];
            #pragma unroll 8
            for (int k = 0; k < K_DIM; ++k) {
                float w = W[k * COLS + c];
                acc0 += xb[0 * K_DIM + k] * w;
                acc1 += xb[1 * K_DIM + k] * w;
                acc2 += xb[2 * K_DIM + k] * w;
                acc3 += xb[3 * K_DIM + k] * w;
            }
            int r0 = rb + g * 4;
            if (r0 + 0 < nrows) out[(size_t)(r0 + 0) * COLS + c] = acc0;
            if (r0 + 1 < nrows) out[(size_t)(r0 + 1) * COLS + c] = acc1;
            if (r0 + 2 < nrows) out[(size_t)(r0 + 2) * COLS + c] = acc2;
            if (r0 + 3 < nrows) out[(size_t)(r0 + 3) * COLS + c] = acc3;
        }
    }
}

// ---------------- per-node attention dots: one wave per row ----------------
template<int COLS>
__global__ void k_node_al(const float* __restrict__ xs, const float* __restrict__ a_src,
                          const float* __restrict__ a_dst,
                          float* __restrict__ al_src, float* __restrict__ al_dst, int n)
{
    int w = (blockIdx.x * blockDim.x + threadIdx.x) >> 6;
    int lane = threadIdx.x & 63;
    if (w >= n) return;
    const float* row = xs + (size_t)w * COLS;
    float s = 0.f, d = 0.f;
    #pragma unroll
    for (int c0 = 0; c0 < COLS; c0 += 64) {
        int c = c0 + lane;
        if (c < COLS) {
            float v = row[c];
            s += v * a_src[c];
            d += v * a_dst[c];
        }
    }
    #pragma unroll
    for (int off = 32; off > 0; off >>= 1) {
        s += __shfl_down(s, off);
        d += __shfl_down(d, off);
    }
    if (lane == 0) { al_src[w] = s; al_dst[w] = d; }
}

// ---------------- edge: alpha -> CSR fill ----------------
__global__ void k_alpha_fill(const int* __restrict__ src, const int* __restrict__ dst,
                             const float* __restrict__ eatt, const float* __restrict__ ve,
                             const float* __restrict__ al_src, const float* __restrict__ al_dst,
                             int* __restrict__ cur, int* __restrict__ csr_src,
                             float* __restrict__ csr_alpha, int E_)
{
    int e = blockIdx.x * blockDim.x + threadIdx.x;
    if (e >= E_) return;
    const float4* ea = reinterpret_cast<const float4*>(eatt + (size_t)e * 8);
    float4 e0 = ea[0], e1 = ea[1];
    float ae = e0.x * ve[0] + e0.y * ve[1] + e0.z * ve[2] + e0.w * ve[3]
             + e1.x * ve[4] + e1.y * ve[5] + e1.z * ve[6] + e1.w * ve[7];
    int d = dst[e];
    int s = src[e];
    float a = al_src[s] + al_dst[d] + ae;
    a = a > 0.f ? a : 0.2f * a;       // leaky_relu(0.2)
    int pos = atomicAdd(&cur[d], 1);
    csr_src[pos] = s;
    csr_alpha[pos] = a;
}

// ---------------- per-dst aggregate: one wave per node ----------------
// out[d,:] = (sum_e exp(a_e - m) * xs[src_e,:]) / (sum_e exp(a_e - m))
template<int COLS>
__global__ void k_aggregate(const int* __restrict__ rp, const int* __restrict__ csr_src,
                            const float* __restrict__ csr_alpha,
                            const float* __restrict__ xs, float* __restrict__ out)
{
    int w = blockIdx.x * 4 + (threadIdx.x >> 6);
    int lane = threadIdx.x & 63;
    if (w >= NN) return;
    int beg = rp[w], end = rp[w + 1];

    // phase 1: segment max (lane-parallel + shuffle reduce)
    float mx = -INFINITY;
    for (int j = beg + lane; j < end; j += 64) mx = fmaxf(mx, csr_alpha[j]);
    #pragma unroll
    for (int off = 32; off > 0; off >>= 1) mx = fmaxf(mx, __shfl_xor(mx, off));

    // phase 2: fused exp-weighted accumulate + denominator
    float acc0 = 0.f, acc1 = 0.f, den = 0.f;
    const int c2 = lane + 64;
    for (int j = beg; j < end; ++j) {
        float ex = __expf(csr_alpha[j] - mx);
        int s = csr_src[j];
        den += ex;
        const float* row = xs + (size_t)s * COLS;
        acc0 += ex * row[lane];
        if (COLS > 64 && c2 < COLS) acc1 += ex * row[c2];
    }
    float inv = (end > beg) ? 1.f / den : 0.f;
    out[(size_t)w * COLS + lane] = acc0 * inv;
    if (COLS > 64 && c2 < COLS) out[(size_t)w * COLS + c2] = acc1 * inv;
}

// ---------------- batchnorm stats ----------------
template<int COLS>
__global__ void k_bn_stats(const float* __restrict__ h, float* __restrict__ sums,
                           float* __restrict__ sqs, int n)
{
    int c = threadIdx.x & 127;
    int g = threadIdx.x >> 7;
    if (c >= COLS) return;
    float s = 0.f, q = 0.f;
    for (int r = blockIdx.x * 2 + g; r < n; r += gridDim.x * 2) {
        float v = h[(size_t)r * COLS + c];
        s += v; q += v * v;
    }
    unsafeAtomicAdd(&sums[c], s);
    unsafeAtomicAdd(&sqs[c], q);
}

// ---------------- batchnorm apply (+ optional relu) ----------------
template<int COLS, bool RELU>
__global__ void k_bn_apply(const float* __restrict__ in, float* __restrict__ out,
                           const float* __restrict__ sums, const float* __restrict__ sqs,
                           const float* __restrict__ gamma, const float* __restrict__ beta,
                           int n)
{
    int idx = blockIdx.x * blockDim.x + threadIdx.x;
    if (idx >= n * COLS) return;
    int c = idx % COLS;
    float invn = 1.0f / (float)n;
    float mean = sums[c] * invn;
    float var  = sqs[c] * invn - mean * mean;     // biased, matches jnp var
    float sc = gamma[c] * rsqrtf(var + 1e-5f);
    float sh = beta[c] - mean * sc;
    float v = in[idx] * sc + sh;
    if (RELU) v = fmaxf(v, 0.f);
    out[idx] = v;
}

extern "C" void kernel_launch(void* const* d_in, const int* in_sizes, int n_in,
                              void* d_out, int out_size, void* d_ws, size_t ws_size,
                              hipStream_t stream)
{
    const float* x    = (const float*)d_in[0];
    const int*   eidx = (const int*)d_in[1];
    const float* eatt = (const float*)d_in[2];
    const float* W0   = (const float*)d_in[3];
    const float* as0  = (const float*)d_in[4];
    const float* ad0  = (const float*)d_in[5];
    const float* We0  = (const float*)d_in[6];
    const float* ae0  = (const float*)d_in[7];
    // d_in[8] = b0 : cancels through BN
    const float* W1   = (const float*)d_in[9];
    const float* as1  = (const float*)d_in[10];
    const float* ad1  = (const float*)d_in[11];
    const float* We1  = (const float*)d_in[12];
    const float* ae1  = (const float*)d_in[13];
    // d_in[14] = b1 : cancels through BN
    const float* bng  = (const float*)d_in[15];
    const float* bnb  = (const float*)d_in[16];
    const float* bnfg = (const float*)d_in[17];
    const float* bnfb = (const float*)d_in[18];

    const int N = NN, E = NE;
    const int* src = eidx;
    const int* dst = eidx + E;

    float* ws = (float*)d_ws;
    size_t off = 0;
    float* xs0 = ws + off;      off += (size_t)N * 128;
    float* h   = ws + off;      off += (size_t)N * 128;
    float* xs1 = ws + off;      off += (size_t)N * 112;
    float* csr_alpha = ws + off;        off += E;
    int*   csr_src = (int*)(ws + off);  off += E;
    int*   rp   = (int*)(ws + off);     off += N + 2;
    int*   cur0 = (int*)(ws + off);     off += N;
    int*   cur1 = (int*)(ws + off);     off += N;
    float* al_s = ws + off;     off += N;
    float* al_d = ws + off;     off += N;
    float* stats = ws + off;    off += 512;
    float* ve = ws + off;       off += 16;
    int* deg = (int*)al_s;      // alias: deg dead before k_node_al writes al_s
    float* out1 = xs0;          // alias: xs0 is dead after layer-0 aggregate

    float* sum0 = stats;
    float* sq0  = stats + 128;
    float* sum1 = stats + 256;
    float* sq1  = stats + 368;

    // ---- init + CSR structure (ws is poisoned 0xAA before every call) ----
    k_init<<<(N + 255) / 256, 256, 0, stream>>>(deg, stats, N, 512);
    k_ve<<<1, 64, 0, stream>>>(We0, ae0, We1, ae1, ve);
    k_deg<<<(E + 255) / 256, 256, 0, stream>>>(dst, deg, E);
    k_scan<<<1, 1024, 0, stream>>>(deg, rp, cur0, cur1);

    // ---- layer 0: 128 -> 128 ----
    k_gemm<128><<<2048, 256, 0, stream>>>(x, W0, xs0, N);
    k_node_al<128><<<(N * 64 + 255) / 256, 256, 0, stream>>>(xs0, as0, ad0, al_s, al_d, N);
    k_alpha_fill<<<(E + 255) / 256, 256, 0, stream>>>(src, dst, eatt, ve, al_s, al_d,
                                                      cur0, csr_src, csr_alpha, E);
    k_aggregate<128><<<(N + 3) / 4, 256, 0, stream>>>(rp, csr_src, csr_alpha, xs0, h);
    k_bn_stats<128><<<1024, 256, 0, stream>>>(h, sum0, sq0, N);
    k_bn_apply<128, true><<<(N * 128 + 255) / 256, 256, 0, stream>>>(h, h, sum0, sq0, bng, bnb, N);

    // ---- layer 1: 128 -> 112 ----
    k_gemm<112><<<2048, 256, 0, stream>>>(h, W1, xs1, N);
    k_node_al<112><<<(N * 64 + 255) / 256, 256, 0, stream>>>(xs1, as1, ad1, al_s, al_d, N);
    k_alpha_fill<<<(E + 255) / 256, 256, 0, stream>>>(src, dst, eatt, ve + 8, al_s, al_d,
                                                      cur1, csr_src, csr_alpha, E);
    k_aggregate<112><<<(N + 3) / 4, 256, 0, stream>>>(rp, csr_src, csr_alpha, xs1, out1);
    k_bn_stats<112><<<1024, 256, 0, stream>>>(out1, sum1, sq1, N);
    k_bn_apply<112, false><<<(N * 112 + 255) / 256, 256, 0, stream>>>(out1, (float*)d_out, sum1, sq1, bnfg, bnfb, N);
}

// Round 3
// 719.068 us; speedup vs baseline: 4.2616x; 1.1842x over previous
//
#include <hip/hip_runtime.h>
#include <math.h>

// GAT 2-layer: N=50000 nodes, E=800000 edges, heads=1
// dims: 128 -> 128 (BN+ReLU) -> 112 (BN)
#define NN 50000
#define NE 800000
constexpr int K_DIM = 128;
#define SCAN_B 256
#define SCAN_NBLK ((NN + SCAN_B - 1) / SCAN_B)   // 196

// ---------------- init ----------------
__global__ void k_init(int* deg, float* stats, int n, int ssize)
{
    int idx = blockIdx.x * blockDim.x + threadIdx.x;
    if (idx < n) deg[idx] = 0;
    if (idx < ssize) stats[idx] = 0.f;
}

// ve[0..7] = We0 @ a_edge0 ; ve[8..15] = We1 @ a_edge1   (heads=1 folding)
__global__ void k_ve(const float* We0, const float* ae0, const float* We1, const float* ae1,
                     float* ve)
{
    int j = threadIdx.x;
    if (j < 8) {
        float s = 0.f;
        for (int c = 0; c < 128; ++c) s += We0[j*128 + c] * ae0[c];
        ve[j] = s;
    } else if (j < 16) {
        int jj = j - 8;
        float s = 0.f;
        for (int c = 0; c < 112; ++c) s += We1[jj*112 + c] * ae1[c];
        ve[8 + jj] = s;
    }
}

// ---------------- CSR build ----------------
__global__ void k_deg(const int* __restrict__ dst, int* __restrict__ deg, int E_)
{
    int e = blockIdx.x * blockDim.x + threadIdx.x;
    if (e < E_) atomicAdd(&deg[dst[e]], 1);
}

// hierarchical scan, stage 1: per-block sums
__global__ void k_scan1(const int* __restrict__ deg, int* __restrict__ partial)
{
    __shared__ int sm[SCAN_B];
    int t = threadIdx.x;
    int idx = blockIdx.x * SCAN_B + t;
    sm[t] = (idx < NN) ? deg[idx] : 0;
    __syncthreads();
    #pragma unroll
    for (int off = SCAN_B / 2; off > 0; off >>= 1) {
        if (t < off) sm[t] += sm[t + off];
        __syncthreads();
    }
    if (t == 0) partial[blockIdx.x] = sm[0];
}

// stage 2: single small block scans the 196 partials (-> exclusive offsets)
__global__ void k_scan2(int* __restrict__ partial)
{
    __shared__ int sm[SCAN_B];
    int t = threadIdx.x;
    int v = (t < SCAN_NBLK) ? partial[t] : 0;
    sm[t] = v;
    __syncthreads();
    #pragma unroll
    for (int off = 1; off < SCAN_B; off <<= 1) {
        int u = (t >= off) ? sm[t - off] : 0;
        __syncthreads();
        sm[t] += u;
        __syncthreads();
    }
    if (t < SCAN_NBLK) partial[t] = (t == 0) ? 0 : sm[t - 1];
}

// stage 3: per-block local scan + global offset -> rp, cur0, cur1
__global__ void k_scan3(const int* __restrict__ deg, const int* __restrict__ partial,
                        int* __restrict__ rp, int* __restrict__ cur0, int* __restrict__ cur1)
{
    __shared__ int sm[SCAN_B];
    int t = threadIdx.x;
    int idx = blockIdx.x * SCAN_B + t;
    int v = (idx < NN) ? deg[idx] : 0;
    sm[t] = v;
    __syncthreads();
    #pragma unroll
    for (int off = 1; off < SCAN_B; off <<= 1) {
        int u = (t >= off) ? sm[t - off] : 0;
        __syncthreads();
        sm[t] += u;
        __syncthreads();
    }
    int excl = partial[blockIdx.x] + ((t == 0) ? 0 : sm[t - 1]);
    if (idx < NN) {
        rp[idx] = excl; cur0[idx] = excl; cur1[idx] = excl;
    }
    if (idx == NN - 1) rp[NN] = excl + v;
}

// ---------------- node GEMM: out[r,c] = sum_k A[r,k]*W[k,c], K=128 ----------------
template<int COLS>
__global__ void k_gemm(const float* __restrict__ A, const float* __restrict__ W,
                       float* __restrict__ out, int nrows)
{
    __shared__ float Xl[8 * K_DIM];     // 8 rows of A
    int c = threadIdx.x & 127;
    int g = threadIdx.x >> 7;           // 0..1 -> rows g*4 .. g*4+3
    for (int rb = blockIdx.x * 8; rb < nrows; rb += gridDim.x * 8) {
        __syncthreads();
        for (int i = threadIdx.x; i < 8 * K_DIM; i += blockDim.x) {
            int r = rb + (i >> 7);
            Xl[i] = (r < nrows) ? A[(size_t)r * K_DIM + (i & 127)] : 0.f;
        }
        __syncthreads();
        if (c < COLS) {
            float acc0 = 0.f, acc1 = 0.f, acc2 = 0.f, acc3 = 0.f;
            const float* xb = &Xl[g * 4 * K_DIM];
            #pragma unroll 8
            for (int k = 0; k < K_DIM; ++k) {
                float w = W[k * COLS + c];
                acc0 += xb[0 * K_DIM + k] * w;
                acc1 += xb[1 * K_DIM + k] * w;
                acc2 += xb[2 * K_DIM + k] * w;
                acc3 += xb[3 * K_DIM + k] * w;
            }
            int r0 = rb + g * 4;
            if (r0 + 0 < nrows) out[(size_t)(r0 + 0) * COLS + c] = acc0;
            if (r0 + 1 < nrows) out[(size_t)(r0 + 1) * COLS + c] = acc1;
            if (r0 + 2 < nrows) out[(size_t)(r0 + 2) * COLS + c] = acc2;
            if (r0 + 3 < nrows) out[(size_t)(r0 + 3) * COLS + c] = acc3;
        }
    }
}

// ---------------- per-node attention dots: one wave per row ----------------
template<int COLS>
__global__ void k_node_al(const float* __restrict__ xs, const float* __restrict__ a_src,
                          const float* __restrict__ a_dst,
                          float* __restrict__ al_src, float* __restrict__ al_dst, int n)
{
    int w = (blockIdx.x * blockDim.x + threadIdx.x) >> 6;
    int lane = threadIdx.x & 63;
    if (w >= n) return;
    const float* row = xs + (size_t)w * COLS;
    float s = 0.f, d = 0.f;
    #pragma unroll
    for (int c0 = 0; c0 < COLS; c0 += 64) {
        int c = c0 + lane;
        if (c < COLS) {
            float v = row[c];
            s += v * a_src[c];
            d += v * a_dst[c];
        }
    }
    #pragma unroll
    for (int off = 32; off > 0; off >>= 1) {
        s += __shfl_down(s, off);
        d += __shfl_down(d, off);
    }
    if (lane == 0) { al_src[w] = s; al_dst[w] = d; }
}

// ---------------- edge: alpha -> CSR fill ----------------
__global__ void k_alpha_fill(const int* __restrict__ src, const int* __restrict__ dst,
                             const float* __restrict__ eatt, const float* __restrict__ ve,
                             const float* __restrict__ al_src, const float* __restrict__ al_dst,
                             int* __restrict__ cur, int* __restrict__ csr_src,
                             float* __restrict__ csr_alpha, int E_)
{
    int e = blockIdx.x * blockDim.x + threadIdx.x;
    if (e >= E_) return;
    const float4* ea = reinterpret_cast<const float4*>(eatt + (size_t)e * 8);
    float4 e0 = ea[0], e1 = ea[1];
    float ae = e0.x * ve[0] + e0.y * ve[1] + e0.z * ve[2] + e0.w * ve[3]
             + e1.x * ve[4] + e1.y * ve[5] + e1.z * ve[6] + e1.w * ve[7];
    int d = dst[e];
    int s = src[e];
    float a = al_src[s] + al_dst[d] + ae;
    a = a > 0.f ? a : 0.2f * a;       // leaky_relu(0.2)
    int pos = atomicAdd(&cur[d], 1);
    csr_src[pos] = s;
    csr_alpha[pos] = a;
}

// ---------------- per-dst aggregate: one wave per node ----------------
// out[d,:] = (sum_e exp(a_e - m) * xs[src_e,:]) / (sum_e exp(a_e - m))
template<int COLS>
__global__ void k_aggregate(const int* __restrict__ rp, const int* __restrict__ csr_src,
                            const float* __restrict__ csr_alpha,
                            const float* __restrict__ xs, float* __restrict__ out)
{
    int w = blockIdx.x * 4 + (threadIdx.x >> 6);
    int lane = threadIdx.x & 63;
    if (w >= NN) return;
    int beg = rp[w], end = rp[w + 1];

    // phase 1: segment max (lane-parallel + shuffle reduce)
    float mx = -INFINITY;
    for (int j = beg + lane; j < end; j += 64) mx = fmaxf(mx, csr_alpha[j]);
    #pragma unroll
    for (int off = 32; off > 0; off >>= 1) mx = fmaxf(mx, __shfl_xor(mx, off));

    // phase 2: fused exp-weighted accumulate + denominator
    float acc0 = 0.f, acc1 = 0.f, den = 0.f;
    const int c2 = lane + 64;
    for (int j = beg; j < end; ++j) {
        float ex = __expf(csr_alpha[j] - mx);
        int s = csr_src[j];
        den += ex;
        const float* row = xs + (size_t)s * COLS;
        acc0 += ex * row[lane];
        if (COLS > 64 && c2 < COLS) acc1 += ex * row[c2];
    }
    float inv = (end > beg) ? 1.f / den : 0.f;
    out[(size_t)w * COLS + lane] = acc0 * inv;
    if (COLS > 64 && c2 < COLS) out[(size_t)w * COLS + c2] = acc1 * inv;
}

// ---------------- batchnorm stats ----------------
template<int COLS>
__global__ void k_bn_stats(const float* __restrict__ h, float* __restrict__ sums,
                           float* __restrict__ sqs, int n)
{
    int c = threadIdx.x & 127;
    int g = threadIdx.x >> 7;
    if (c >= COLS) return;
    float s = 0.f, q = 0.f;
    for (int r = blockIdx.x * 2 + g; r < n; r += gridDim.x * 2) {
        float v = h[(size_t)r * COLS + c];
        s += v; q += v * v;
    }
    unsafeAtomicAdd(&sums[c], s);
    unsafeAtomicAdd(&sqs[c], q);
}

// ---------------- batchnorm apply (+ optional relu) ----------------
template<int COLS, bool RELU>
__global__ void k_bn_apply(const float* __restrict__ in, float* __restrict__ out,
                           const float* __restrict__ sums, const float* __restrict__ sqs,
                           const float* __restrict__ gamma, const float* __restrict__ beta,
                           int n)
{
    int idx = blockIdx.x * blockDim.x + threadIdx.x;
    if (idx >= n * COLS) return;
    int c = idx % COLS;
    float invn = 1.0f / (float)n;
    float mean = sums[c] * invn;
    float var  = sqs[c] * invn - mean * mean;     // biased, matches jnp var
    float sc = gamma[c] * rsqrtf(var + 1e-5f);
    float sh = beta[c] - mean * sc;
    float v = in[idx] * sc + sh;
    if (RELU) v = fmaxf(v, 0.f);
    out[idx] = v;
}

extern "C" void kernel_launch(void* const* d_in, const int* in_sizes, int n_in,
                              void* d_out, int out_size, void* d_ws, size_t ws_size,
                              hipStream_t stream)
{
    const float* x    = (const float*)d_in[0];
    const int*   eidx = (const int*)d_in[1];
    const float* eatt = (const float*)d_in[2];
    const float* W0   = (const float*)d_in[3];
    const float* as0  = (const float*)d_in[4];
    const float* ad0  = (const float*)d_in[5];
    const float* We0  = (const float*)d_in[6];
    const float* ae0  = (const float*)d_in[7];
    // d_in[8] = b0 : cancels through BN
    const float* W1   = (const float*)d_in[9];
    const float* as1  = (const float*)d_in[10];
    const float* ad1  = (const float*)d_in[11];
    const float* We1  = (const float*)d_in[12];
    const float* ae1  = (const float*)d_in[13];
    // d_in[14] = b1 : cancels through BN
    const float* bng  = (const float*)d_in[15];
    const float* bnb  = (const float*)d_in[16];
    const float* bnfg = (const float*)d_in[17];
    const float* bnfb = (const float*)d_in[18];

    const int N = NN, E = NE;
    const int* src = eidx;
    const int* dst = eidx + E;

    float* ws = (float*)d_ws;
    size_t off = 0;
    float* xs0 = ws + off;      off += (size_t)N * 128;
    float* h   = ws + off;      off += (size_t)N * 128;
    float* xs1 = ws + off;      off += (size_t)N * 112;
    float* csr_alpha = ws + off;        off += E;
    int*   csr_src = (int*)(ws + off);  off += E;
    int*   rp   = (int*)(ws + off);     off += N + 2;
    int*   cur0 = (int*)(ws + off);     off += N;
    int*   cur1 = (int*)(ws + off);     off += N;
    float* al_s = ws + off;     off += N;
    float* al_d = ws + off;     off += N;
    float* stats = ws + off;    off += 512;
    float* ve = ws + off;       off += 16;
    int*   partial = (int*)(ws + off);  off += SCAN_NBLK;
    int* deg = (int*)al_s;      // alias: deg dead before k_node_al writes al_s
    float* out1 = xs0;          // alias: xs0 is dead after layer-0 aggregate

    float* sum0 = stats;
    float* sq0  = stats + 128;
    float* sum1 = stats + 256;
    float* sq1  = stats + 368;

    // ---- init + CSR structure (ws is poisoned 0xAA before every call) ----
    k_init<<<(N + 255) / 256, 256, 0, stream>>>(deg, stats, N, 512);
    k_ve<<<1, 64, 0, stream>>>(We0, ae0, We1, ae1, ve);
    k_deg<<<(E + 255) / 256, 256, 0, stream>>>(dst, deg, E);
    k_scan1<<<SCAN_NBLK, SCAN_B, 0, stream>>>(deg, partial);
    k_scan2<<<1, SCAN_B, 0, stream>>>(partial);
    k_scan3<<<SCAN_NBLK, SCAN_B, 0, stream>>>(deg, partial, rp, cur0, cur1);

    // ---- layer 0: 128 -> 128 ----
    k_gemm<128><<<6250, 256, 0, stream>>>(x, W0, xs0, N);
    k_node_al<128><<<(N * 64 + 255) / 256, 256, 0, stream>>>(xs0, as0, ad0, al_s, al_d, N);
    k_alpha_fill<<<(E + 255) / 256, 256, 0, stream>>>(src, dst, eatt, ve, al_s, al_d,
                                                      cur0, csr_src, csr_alpha, E);
    k_aggregate<128><<<(N + 3) / 4, 256, 0, stream>>>(rp, csr_src, csr_alpha, xs0, h);
    k_bn_stats<128><<<1024, 256, 0, stream>>>(h, sum0, sq0, N);
    k_bn_apply<128, true><<<(N * 128 + 255) / 256, 256, 0, stream>>>(h, h, sum0, sq0, bng, bnb, N);

    // ---- layer 1: 128 -> 112 ----
    k_gemm<112><<<6250, 256, 0, stream>>>(h, W1, xs1, N);
    k_node_al<112><<<(N * 64 + 255) / 256, 256, 0, stream>>>(xs1, as1, ad1, al_s, al_d, N);
    k_alpha_fill<<<(E + 255) / 256, 256, 0, stream>>>(src, dst, eatt, ve + 8, al_s, al_d,
                                                      cur1, csr_src, csr_alpha, E);
    k_aggregate<112><<<(N + 3) / 4, 256, 0, stream>>>(rp, csr_src, csr_alpha, xs1, out1);
    k_bn_stats<112><<<1024, 256, 0, stream>>>(out1, sum1, sq1, N);
    k_bn_apply<112, false><<<(N * 112 + 255) / 256, 256, 0, stream>>>(out1, (float*)d_out, sum1, sq1, bnfg, bnfb, N);
}

// Round 4
// 598.192 us; speedup vs baseline: 5.1227x; 1.2021x over previous
//
#include <hip/hip_runtime.h>
#include <math.h>

// GAT 2-layer: N=50000 nodes, E=800000 edges, heads=1
// dims: 128 -> 128 (BN+ReLU) -> 112 (BN)
#define NN 50000
#define NE 800000
constexpr int K_DIM = 128;
#define SCAN_B 256
#define SCAN_NBLK ((NN + SCAN_B - 1) / SCAN_B)   // 196

struct EdgePack { int s; float a0, a1; };        // 12 B, one line per edge

__device__ __forceinline__ unsigned short f2bf(float x) {
    unsigned u = __float_as_uint(x);
    u += 0x7fffu + ((u >> 16) & 1);              // round-to-nearest-even
    return (unsigned short)(u >> 16);
}
__device__ __forceinline__ float bf2f(unsigned short h) {
    return __uint_as_float(((unsigned)h) << 16);
}

// ---------------- init ----------------
__global__ void k_init(int* deg, float* als0, float* ald0, float* als1, float* ald1,
                       float* stats, int n, int ssize)
{
    int idx = blockIdx.x * blockDim.x + threadIdx.x;
    if (idx < n) {
        deg[idx] = 0;
        als0[idx] = 0.f; ald0[idx] = 0.f;
        als1[idx] = 0.f; ald1[idx] = 0.f;
    }
    if (idx < ssize) stats[idx] = 0.f;
}

// ve[0..7] = We0 @ a_edge0 ; ve[8..15] = We1 @ a_edge1   (heads=1 folding)
__global__ void k_ve(const float* We0, const float* ae0, const float* We1, const float* ae1,
                     float* ve)
{
    int j = threadIdx.x;
    if (j < 8) {
        float s = 0.f;
        for (int c = 0; c < 128; ++c) s += We0[j*128 + c] * ae0[c];
        ve[j] = s;
    } else if (j < 16) {
        int jj = j - 8;
        float s = 0.f;
        for (int c = 0; c < 112; ++c) s += We1[jj*112 + c] * ae1[c];
        ve[8 + jj] = s;
    }
}

// ---------------- CSR build ----------------
__global__ void k_deg(const int* __restrict__ dst, int* __restrict__ deg, int E_)
{
    int e = blockIdx.x * blockDim.x + threadIdx.x;
    if (e < E_) atomicAdd(&deg[dst[e]], 1);
}

__global__ void k_scan1(const int* __restrict__ deg, int* __restrict__ partial)
{
    __shared__ int sm[SCAN_B];
    int t = threadIdx.x;
    int idx = blockIdx.x * SCAN_B + t;
    sm[t] = (idx < NN) ? deg[idx] : 0;
    __syncthreads();
    #pragma unroll
    for (int off = SCAN_B / 2; off > 0; off >>= 1) {
        if (t < off) sm[t] += sm[t + off];
        __syncthreads();
    }
    if (t == 0) partial[blockIdx.x] = sm[0];
}

__global__ void k_scan2(int* __restrict__ partial)
{
    __shared__ int sm[SCAN_B];
    int t = threadIdx.x;
    int v = (t < SCAN_NBLK) ? partial[t] : 0;
    sm[t] = v;
    __syncthreads();
    #pragma unroll
    for (int off = 1; off < SCAN_B; off <<= 1) {
        int u = (t >= off) ? sm[t - off] : 0;
        __syncthreads();
        sm[t] += u;
        __syncthreads();
    }
    if (t < SCAN_NBLK) partial[t] = (t == 0) ? 0 : sm[t - 1];
}

__global__ void k_scan3(const int* __restrict__ deg, const int* __restrict__ partial,
                        int* __restrict__ rp, int* __restrict__ cur)
{
    __shared__ int sm[SCAN_B];
    int t = threadIdx.x;
    int idx = blockIdx.x * SCAN_B + t;
    int v = (idx < NN) ? deg[idx] : 0;
    sm[t] = v;
    __syncthreads();
    #pragma unroll
    for (int off = 1; off < SCAN_B; off <<= 1) {
        int u = (t >= off) ? sm[t - off] : 0;
        __syncthreads();
        sm[t] += u;
        __syncthreads();
    }
    int excl = partial[blockIdx.x] + ((t == 0) ? 0 : sm[t - 1]);
    if (idx < NN) { rp[idx] = excl; cur[idx] = excl; }
    if (idx == NN - 1) rp[NN] = excl + v;
}

// ---------------- edge pack: per-edge attention dots for BOTH layers, CSR order ----------------
__global__ void k_csr_fill(const int* __restrict__ src, const int* __restrict__ dst,
                           const float* __restrict__ eatt, const float* __restrict__ ve,
                           int* __restrict__ cur, EdgePack* __restrict__ pack, int E_)
{
    int e = blockIdx.x * blockDim.x + threadIdx.x;
    if (e >= E_) return;
    const float4* ea = reinterpret_cast<const float4*>(eatt + (size_t)e * 8);
    float4 e0 = ea[0], e1 = ea[1];
    float a0 = e0.x * ve[0] + e0.y * ve[1] + e0.z * ve[2] + e0.w * ve[3]
             + e1.x * ve[4] + e1.y * ve[5] + e1.z * ve[6] + e1.w * ve[7];
    float a1 = e0.x * ve[8] + e0.y * ve[9] + e0.z * ve[10] + e0.w * ve[11]
             + e1.x * ve[12] + e1.y * ve[13] + e1.z * ve[14] + e1.w * ve[15];
    int d = dst[e];
    int pos = atomicAdd(&cur[d], 1);
    EdgePack p; p.s = src[e]; p.a0 = a0; p.a1 = a1;
    pack[pos] = p;
}

// ---------------- node GEMM: bf16 out + fused attention-dot epilogue ----------------
// out[r,c] = sum_k A[r,k]*W[k,c]  (fp32 acc -> bf16 store)
// als[r] += sum_c out[r,c]*a_src[c] ; ald[r] += ... a_dst[c]   (fp32, atomics)
template<int COLS>
__global__ void k_gemm(const float* __restrict__ A, const float* __restrict__ W,
                       unsigned short* __restrict__ out,
                       const float* __restrict__ a_src, const float* __restrict__ a_dst,
                       float* __restrict__ als, float* __restrict__ ald)
{
    __shared__ float Xl[8 * K_DIM];     // 8 rows of A
    int c = threadIdx.x & 127;
    int g = threadIdx.x >> 7;           // 0..1 -> rows g*4 .. g*4+3
    int lane = threadIdx.x & 63;
    int rb = blockIdx.x * 8;            // grid is exactly NN/8

    for (int i = threadIdx.x; i < 8 * K_DIM; i += blockDim.x) {
        int r = rb + (i >> 7);
        Xl[i] = A[(size_t)r * K_DIM + (i & 127)];
    }
    __syncthreads();

    int cc = (c < COLS) ? c : 0;        // clamp to stay in-bounds for W
    float acc0 = 0.f, acc1 = 0.f, acc2 = 0.f, acc3 = 0.f;
    const float* xb = &Xl[g * 4 * K_DIM];
    #pragma unroll 8
    for (int k = 0; k < K_DIM; ++k) {
        float w = W[k * COLS + cc];
        acc0 += xb[0 * K_DIM + k] * w;
        acc1 += xb[1 * K_DIM + k] * w;
        acc2 += xb[2 * K_DIM + k] * w;
        acc3 += xb[3 * K_DIM + k] * w;
    }
    int r0 = rb + g * 4;
    if (c < COLS) {
        out[(size_t)(r0 + 0) * COLS + c] = f2bf(acc0);
        out[(size_t)(r0 + 1) * COLS + c] = f2bf(acc1);
        out[(size_t)(r0 + 2) * COLS + c] = f2bf(acc2);
        out[(size_t)(r0 + 3) * COLS + c] = f2bf(acc3);
    }
    // fused attention dots (fp32 accs): mask inactive cols with 0 weight
    float asv = (c < COLS) ? a_src[c] : 0.f;
    float adv = (c < COLS) ? a_dst[c] : 0.f;
    float p0 = acc0 * asv, p1 = acc1 * asv, p2 = acc2 * asv, p3 = acc3 * asv;
    float q0 = acc0 * adv, q1 = acc1 * adv, q2 = acc2 * adv, q3 = acc3 * adv;
    #pragma unroll
    for (int off = 32; off > 0; off >>= 1) {
        p0 += __shfl_down(p0, off); p1 += __shfl_down(p1, off);
        p2 += __shfl_down(p2, off); p3 += __shfl_down(p3, off);
        q0 += __shfl_down(q0, off); q1 += __shfl_down(q1, off);
        q2 += __shfl_down(q2, off); q3 += __shfl_down(q3, off);
    }
    if (lane == 0) {
        unsafeAtomicAdd(&als[r0 + 0], p0); unsafeAtomicAdd(&als[r0 + 1], p1);
        unsafeAtomicAdd(&als[r0 + 2], p2); unsafeAtomicAdd(&als[r0 + 3], p3);
        unsafeAtomicAdd(&ald[r0 + 0], q0); unsafeAtomicAdd(&ald[r0 + 1], q1);
        unsafeAtomicAdd(&ald[r0 + 2], q2); unsafeAtomicAdd(&ald[r0 + 3], q3);
    }
}

// ---------------- per-dst aggregate: one wave per node, bf16 gather ----------------
// out[d,:] = (sum_e exp(alpha_e) * xs[src_e,:]) / (sum_e exp(alpha_e))
// (no max-subtraction: |alpha| <~ 10 here; exp is safe in fp32 and ratio is identical)
template<int COLS, int LAYER>
__global__ void k_aggregate(const int* __restrict__ rp, const EdgePack* __restrict__ pack,
                            const float* __restrict__ als, const float* __restrict__ ald,
                            const unsigned short* __restrict__ xs, float* __restrict__ out)
{
    int w = blockIdx.x * 4 + (threadIdx.x >> 6);
    int lane = threadIdx.x & 63;
    if (w >= NN) return;
    int beg = rp[w], end = rp[w + 1];
    float aldv = ald[w];
    int col = lane * 2;
    bool act = (col < COLS);

    float acc0 = 0.f, acc1 = 0.f, den = 0.f;
    int j = beg;
    for (; j + 2 <= end; j += 2) {
        EdgePack pA = pack[j];
        EdgePack pB = pack[j + 1];
        float aA = als[pA.s] + aldv + (LAYER ? pA.a1 : pA.a0);
        float aB = als[pB.s] + aldv + (LAYER ? pB.a1 : pB.a0);
        aA = aA > 0.f ? aA : 0.2f * aA;
        aB = aB > 0.f ? aB : 0.2f * aB;
        float exA = __expf(aA), exB = __expf(aB);
        den += exA + exB;
        if (act) {
            ushort2 uA = *reinterpret_cast<const ushort2*>(xs + (size_t)pA.s * COLS + col);
            ushort2 uB = *reinterpret_cast<const ushort2*>(xs + (size_t)pB.s * COLS + col);
            acc0 += exA * bf2f(uA.x) + exB * bf2f(uB.x);
            acc1 += exA * bf2f(uA.y) + exB * bf2f(uB.y);
        }
    }
    if (j < end) {
        EdgePack p = pack[j];
        float a = als[p.s] + aldv + (LAYER ? p.a1 : p.a0);
        a = a > 0.f ? a : 0.2f * a;
        float ex = __expf(a);
        den += ex;
        if (act) {
            ushort2 u = *reinterpret_cast<const ushort2*>(xs + (size_t)p.s * COLS + col);
            acc0 += ex * bf2f(u.x);
            acc1 += ex * bf2f(u.y);
        }
    }
    float inv = (end > beg) ? 1.f / den : 0.f;
    if (act) {
        float2 o; o.x = acc0 * inv; o.y = acc1 * inv;
        *reinterpret_cast<float2*>(out + (size_t)w * COLS + col) = o;
    }
}

// ---------------- batchnorm stats ----------------
template<int COLS>
__global__ void k_bn_stats(const float* __restrict__ h, float* __restrict__ sums,
                           float* __restrict__ sqs, int n)
{
    int c = threadIdx.x & 127;
    int g = threadIdx.x >> 7;
    if (c >= COLS) return;
    float s = 0.f, q = 0.f;
    for (int r = blockIdx.x * 2 + g; r < n; r += gridDim.x * 2) {
        float v = h[(size_t)r * COLS + c];
        s += v; q += v * v;
    }
    unsafeAtomicAdd(&sums[c], s);
    unsafeAtomicAdd(&sqs[c], q);
}

// ---------------- batchnorm apply (+ optional relu) ----------------
template<int COLS, bool RELU>
__global__ void k_bn_apply(const float* __restrict__ in, float* __restrict__ out,
                           const float* __restrict__ sums, const float* __restrict__ sqs,
                           const float* __restrict__ gamma, const float* __restrict__ beta,
                           int n)
{
    int idx = blockIdx.x * blockDim.x + threadIdx.x;
    if (idx >= n * COLS) return;
    int c = idx % COLS;
    float invn = 1.0f / (float)n;
    float mean = sums[c] * invn;
    float var  = sqs[c] * invn - mean * mean;     // biased, matches jnp var
    float sc = gamma[c] * rsqrtf(var + 1e-5f);
    float sh = beta[c] - mean * sc;
    float v = in[idx] * sc + sh;
    if (RELU) v = fmaxf(v, 0.f);
    out[idx] = v;
}

extern "C" void kernel_launch(void* const* d_in, const int* in_sizes, int n_in,
                              void* d_out, int out_size, void* d_ws, size_t ws_size,
                              hipStream_t stream)
{
    const float* x    = (const float*)d_in[0];
    const int*   eidx = (const int*)d_in[1];
    const float* eatt = (const float*)d_in[2];
    const float* W0   = (const float*)d_in[3];
    const float* as0  = (const float*)d_in[4];
    const float* ad0  = (const float*)d_in[5];
    const float* We0  = (const float*)d_in[6];
    const float* ae0  = (const float*)d_in[7];
    // d_in[8] = b0 : cancels through BN
    const float* W1   = (const float*)d_in[9];
    const float* as1  = (const float*)d_in[10];
    const float* ad1  = (const float*)d_in[11];
    const float* We1  = (const float*)d_in[12];
    const float* ae1  = (const float*)d_in[13];
    // d_in[14] = b1 : cancels through BN
    const float* bng  = (const float*)d_in[15];
    const float* bnb  = (const float*)d_in[16];
    const float* bnfg = (const float*)d_in[17];
    const float* bnfb = (const float*)d_in[18];

    const int N = NN, E = NE;
    const int* src = eidx;
    const int* dst = eidx + E;

    float* ws = (float*)d_ws;
    size_t off = 0;
    unsigned short* xs0b = (unsigned short*)(ws + off); off += (size_t)N * 64;   // N*128 bf16
    float* h   = ws + off;      off += (size_t)N * 128;                          // fp32; out1 aliases
    unsigned short* xs1b = (unsigned short*)(ws + off); off += (size_t)N * 56;   // N*112 bf16
    EdgePack* pack = (EdgePack*)(ws + off);             off += (size_t)E * 3;
    int*   rp   = (int*)(ws + off);     off += N + 2;
    int*   cur  = (int*)(ws + off);     off += N;
    int*   deg  = (int*)(ws + off);     off += N;
    float* als0 = ws + off;     off += N;
    float* ald0 = ws + off;     off += N;
    float* als1 = ws + off;     off += N;
    float* ald1 = ws + off;     off += N;
    float* stats = ws + off;    off += 512;
    float* ve = ws + off;       off += 16;
    int*   partial = (int*)(ws + off);  off += SCAN_NBLK;
    float* out1 = h;            // alias: h dead after layer-1 gemm consumes it

    float* sum0 = stats;
    float* sq0  = stats + 128;
    float* sum1 = stats + 256;
    float* sq1  = stats + 368;

    // ---- init + CSR structure (ws is poisoned 0xAA before every call) ----
    k_init<<<(N + 255) / 256, 256, 0, stream>>>(deg, als0, ald0, als1, ald1, stats, N, 512);
    k_ve<<<1, 64, 0, stream>>>(We0, ae0, We1, ae1, ve);
    k_deg<<<(E + 255) / 256, 256, 0, stream>>>(dst, deg, E);
    k_scan1<<<SCAN_NBLK, SCAN_B, 0, stream>>>(deg, partial);
    k_scan2<<<1, SCAN_B, 0, stream>>>(partial);
    k_scan3<<<SCAN_NBLK, SCAN_B, 0, stream>>>(deg, partial, rp, cur);
    k_csr_fill<<<(E + 255) / 256, 256, 0, stream>>>(src, dst, eatt, ve, cur, pack, E);

    // ---- layer 0: 128 -> 128 ----
    k_gemm<128><<<N / 8, 256, 0, stream>>>(x, W0, xs0b, as0, ad0, als0, ald0);
    k_aggregate<128, 0><<<(N + 3) / 4, 256, 0, stream>>>(rp, pack, als0, ald0, xs0b, h);
    k_bn_stats<128><<<1024, 256, 0, stream>>>(h, sum0, sq0, N);
    k_bn_apply<128, true><<<(N * 128 + 255) / 256, 256, 0, stream>>>(h, h, sum0, sq0, bng, bnb, N);

    // ---- layer 1: 128 -> 112 ----
    k_gemm<112><<<N / 8, 256, 0, stream>>>(h, W1, xs1b, as1, ad1, als1, ald1);
    k_aggregate<112, 1><<<(N + 3) / 4, 256, 0, stream>>>(rp, pack, als1, ald1, xs1b, out1);
    k_bn_stats<112><<<1024, 256, 0, stream>>>(out1, sum1, sq1, N);
    k_bn_apply<112, false><<<(N * 112 + 255) / 256, 256, 0, stream>>>(out1, (float*)d_out, sum1, sq1, bnfg, bnfb, N);
}

// Round 5
// 521.610 us; speedup vs baseline: 5.8748x; 1.1468x over previous
//
#include <hip/hip_runtime.h>
#include <math.h>

// GAT 2-layer: N=50000 nodes, E=800000 edges, heads=1
// dims: 128 -> 128 (BN+ReLU) -> 112 (BN)
#define NN 50000
#define NE 800000
constexpr int K_DIM = 128;
#define SCAN_B 256
#define SCAN_NBLK ((NN + SCAN_B - 1) / SCAN_B)   // 196
#define BN_NBLK 256

struct EdgePack { int s; float a0, a1; };        // 12 B, one record per edge

__device__ __forceinline__ unsigned short f2bf(float x) {
    unsigned u = __float_as_uint(x);
    u += 0x7fffu + ((u >> 16) & 1);              // round-to-nearest-even
    return (unsigned short)(u >> 16);
}
__device__ __forceinline__ float bf2f(unsigned short h) {
    return __uint_as_float(((unsigned)h) << 16);
}

// ---------------- init ----------------
__global__ void k_init(int* deg, float* als0, float* ald0, float* als1, float* ald1, int n)
{
    int idx = blockIdx.x * blockDim.x + threadIdx.x;
    if (idx < n) {
        deg[idx] = 0;
        als0[idx] = 0.f; ald0[idx] = 0.f;
        als1[idx] = 0.f; ald1[idx] = 0.f;
    }
}

// ve[0..7] = We0 @ a_edge0 ; ve[8..15] = We1 @ a_edge1   (heads=1 folding)
__global__ void k_ve(const float* We0, const float* ae0, const float* We1, const float* ae1,
                     float* ve)
{
    int j = threadIdx.x;
    if (j < 8) {
        float s = 0.f;
        for (int c = 0; c < 128; ++c) s += We0[j*128 + c] * ae0[c];
        ve[j] = s;
    } else if (j < 16) {
        int jj = j - 8;
        float s = 0.f;
        for (int c = 0; c < 112; ++c) s += We1[jj*112 + c] * ae1[c];
        ve[8 + jj] = s;
    }
}

// ---------------- CSR build ----------------
__global__ void k_deg(const int* __restrict__ dst, int* __restrict__ deg, int E_)
{
    int e = blockIdx.x * blockDim.x + threadIdx.x;
    if (e < E_) atomicAdd(&deg[dst[e]], 1);
}

__global__ void k_scan1(const int* __restrict__ deg, int* __restrict__ partial)
{
    __shared__ int sm[SCAN_B];
    int t = threadIdx.x;
    int idx = blockIdx.x * SCAN_B + t;
    sm[t] = (idx < NN) ? deg[idx] : 0;
    __syncthreads();
    #pragma unroll
    for (int off = SCAN_B / 2; off > 0; off >>= 1) {
        if (t < off) sm[t] += sm[t + off];
        __syncthreads();
    }
    if (t == 0) partial[blockIdx.x] = sm[0];
}

__global__ void k_scan2(int* __restrict__ partial)
{
    __shared__ int sm[SCAN_B];
    int t = threadIdx.x;
    int v = (t < SCAN_NBLK) ? partial[t] : 0;
    sm[t] = v;
    __syncthreads();
    #pragma unroll
    for (int off = 1; off < SCAN_B; off <<= 1) {
        int u = (t >= off) ? sm[t - off] : 0;
        __syncthreads();
        sm[t] += u;
        __syncthreads();
    }
    if (t < SCAN_NBLK) partial[t] = (t == 0) ? 0 : sm[t - 1];
}

__global__ void k_scan3(const int* __restrict__ deg, const int* __restrict__ partial,
                        int* __restrict__ rp, int* __restrict__ cur)
{
    __shared__ int sm[SCAN_B];
    int t = threadIdx.x;
    int idx = blockIdx.x * SCAN_B + t;
    int v = (idx < NN) ? deg[idx] : 0;
    sm[t] = v;
    __syncthreads();
    #pragma unroll
    for (int off = 1; off < SCAN_B; off <<= 1) {
        int u = (t >= off) ? sm[t - off] : 0;
        __syncthreads();
        sm[t] += u;
        __syncthreads();
    }
    int excl = partial[blockIdx.x] + ((t == 0) ? 0 : sm[t - 1]);
    if (idx < NN) { rp[idx] = excl; cur[idx] = excl; }
    if (idx == NN - 1) rp[NN] = excl + v;
}

// ---------------- edge pack: per-edge attention dots for BOTH layers, CSR order ----------------
__global__ void k_csr_fill(const int* __restrict__ src, const int* __restrict__ dst,
                           const float* __restrict__ eatt, const float* __restrict__ ve,
                           int* __restrict__ cur, EdgePack* __restrict__ pack, int E_)
{
    int e = blockIdx.x * blockDim.x + threadIdx.x;
    if (e >= E_) return;
    const float4* ea = reinterpret_cast<const float4*>(eatt + (size_t)e * 8);
    float4 e0 = ea[0], e1 = ea[1];
    float a0 = e0.x * ve[0] + e0.y * ve[1] + e0.z * ve[2] + e0.w * ve[3]
             + e1.x * ve[4] + e1.y * ve[5] + e1.z * ve[6] + e1.w * ve[7];
    float a1 = e0.x * ve[8] + e0.y * ve[9] + e0.z * ve[10] + e0.w * ve[11]
             + e1.x * ve[12] + e1.y * ve[13] + e1.z * ve[14] + e1.w * ve[15];
    int d = dst[e];
    int pos = atomicAdd(&cur[d], 1);
    EdgePack p; p.s = src[e]; p.a0 = a0; p.a1 = a1;
    pack[pos] = p;
}

// ---------------- node GEMM: bf16 out + fused attention-dot epilogue ----------------
// BN_IN: apply batchnorm+relu (from sums/sqs) to A rows while staging into LDS.
template<int COLS, bool BN_IN>
__global__ void k_gemm(const float* __restrict__ A, const float* __restrict__ W,
                       unsigned short* __restrict__ out,
                       const float* __restrict__ a_src, const float* __restrict__ a_dst,
                       float* __restrict__ als, float* __restrict__ ald,
                       const float* __restrict__ bsum, const float* __restrict__ bsq,
                       const float* __restrict__ gamma, const float* __restrict__ beta)
{
    __shared__ float Xl[8 * K_DIM];     // 8 rows of A
    __shared__ float scN[K_DIM], shN[K_DIM];
    int c = threadIdx.x & 127;
    int g = threadIdx.x >> 7;           // 0..1 -> rows g*4 .. g*4+3
    int lane = threadIdx.x & 63;
    int rb = blockIdx.x * 8;            // grid is exactly NN/8

    if (BN_IN) {
        if (threadIdx.x < K_DIM) {
            int k = threadIdx.x;
            float invn = 1.0f / (float)NN;
            float mean = bsum[k] * invn;
            float var  = bsq[k] * invn - mean * mean;
            float sc = gamma[k] * rsqrtf(var + 1e-5f);
            scN[k] = sc;
            shN[k] = beta[k] - mean * sc;
        }
        __syncthreads();
    }

    for (int i = threadIdx.x; i < 8 * K_DIM; i += blockDim.x) {
        int r = rb + (i >> 7);
        int k = i & 127;
        float v = A[(size_t)r * K_DIM + k];
        if (BN_IN) v = fmaxf(v * scN[k] + shN[k], 0.f);
        Xl[i] = v;
    }
    __syncthreads();

    int cc = (c < COLS) ? c : 0;        // clamp to stay in-bounds for W
    float acc0 = 0.f, acc1 = 0.f, acc2 = 0.f, acc3 = 0.f;
    const float* xb = &Xl[g * 4 * K_DIM];
    #pragma unroll 8
    for (int k = 0; k < K_DIM; ++k) {
        float w = W[k * COLS + cc];
        acc0 += xb[0 * K_DIM + k] * w;
        acc1 += xb[1 * K_DIM + k] * w;
        acc2 += xb[2 * K_DIM + k] * w;
        acc3 += xb[3 * K_DIM + k] * w;
    }
    int r0 = rb + g * 4;
    if (c < COLS) {
        out[(size_t)(r0 + 0) * COLS + c] = f2bf(acc0);
        out[(size_t)(r0 + 1) * COLS + c] = f2bf(acc1);
        out[(size_t)(r0 + 2) * COLS + c] = f2bf(acc2);
        out[(size_t)(r0 + 3) * COLS + c] = f2bf(acc3);
    }
    // fused attention dots (fp32 accs): mask inactive cols with 0 weight
    float asv = (c < COLS) ? a_src[c] : 0.f;
    float adv = (c < COLS) ? a_dst[c] : 0.f;
    float p0 = acc0 * asv, p1 = acc1 * asv, p2 = acc2 * asv, p3 = acc3 * asv;
    float q0 = acc0 * adv, q1 = acc1 * adv, q2 = acc2 * adv, q3 = acc3 * adv;
    #pragma unroll
    for (int off = 32; off > 0; off >>= 1) {
        p0 += __shfl_down(p0, off); p1 += __shfl_down(p1, off);
        p2 += __shfl_down(p2, off); p3 += __shfl_down(p3, off);
        q0 += __shfl_down(q0, off); q1 += __shfl_down(q1, off);
        q2 += __shfl_down(q2, off); q3 += __shfl_down(q3, off);
    }
    if (lane == 0) {
        unsafeAtomicAdd(&als[r0 + 0], p0); unsafeAtomicAdd(&als[r0 + 1], p1);
        unsafeAtomicAdd(&als[r0 + 2], p2); unsafeAtomicAdd(&als[r0 + 3], p3);
        unsafeAtomicAdd(&ald[r0 + 0], q0); unsafeAtomicAdd(&ald[r0 + 1], q1);
        unsafeAtomicAdd(&ald[r0 + 2], q2); unsafeAtomicAdd(&ald[r0 + 3], q3);
    }
}

// ---------------- per-dst aggregate: one wave per node, bf16 gather ----------------
template<int COLS, int LAYER>
__global__ void k_aggregate(const int* __restrict__ rp, const EdgePack* __restrict__ pack,
                            const float* __restrict__ als, const float* __restrict__ ald,
                            const unsigned short* __restrict__ xs, float* __restrict__ out)
{
    int w = blockIdx.x * 4 + (threadIdx.x >> 6);
    int lane = threadIdx.x & 63;
    if (w >= NN) return;
    int beg = rp[w], end = rp[w + 1];
    float aldv = ald[w];
    int col = lane * 2;
    bool act = (col < COLS);

    float acc0 = 0.f, acc1 = 0.f, den = 0.f;
    int j = beg;
    for (; j + 2 <= end; j += 2) {
        EdgePack pA = pack[j];
        EdgePack pB = pack[j + 1];
        float aA = als[pA.s] + aldv + (LAYER ? pA.a1 : pA.a0);
        float aB = als[pB.s] + aldv + (LAYER ? pB.a1 : pB.a0);
        aA = aA > 0.f ? aA : 0.2f * aA;
        aB = aB > 0.f ? aB : 0.2f * aB;
        float exA = __expf(aA), exB = __expf(aB);
        den += exA + exB;
        if (act) {
            ushort2 uA = *reinterpret_cast<const ushort2*>(xs + (size_t)pA.s * COLS + col);
            ushort2 uB = *reinterpret_cast<const ushort2*>(xs + (size_t)pB.s * COLS + col);
            acc0 += exA * bf2f(uA.x) + exB * bf2f(uB.x);
            acc1 += exA * bf2f(uA.y) + exB * bf2f(uB.y);
        }
    }
    if (j < end) {
        EdgePack p = pack[j];
        float a = als[p.s] + aldv + (LAYER ? p.a1 : p.a0);
        a = a > 0.f ? a : 0.2f * a;
        float ex = __expf(a);
        den += ex;
        if (act) {
            ushort2 u = *reinterpret_cast<const ushort2*>(xs + (size_t)p.s * COLS + col);
            acc0 += ex * bf2f(u.x);
            acc1 += ex * bf2f(u.y);
        }
    }
    float inv = (end > beg) ? 1.f / den : 0.f;
    if (act) {
        float2 o; o.x = acc0 * inv; o.y = acc1 * inv;
        *reinterpret_cast<float2*>(out + (size_t)w * COLS + col) = o;
    }
}

// ---------------- batchnorm stats, stage 1: per-block partials (no atomics) ----------------
template<int COLS>
__global__ void k_bn_stats1(const float* __restrict__ h, float* __restrict__ psum,
                            float* __restrict__ psq)
{
    __shared__ float sm[256], sq[256];
    int t = threadIdx.x;
    int c = t & 127;
    int g = t >> 7;
    float s = 0.f, q = 0.f;
    if (c < COLS) {
        for (int r = blockIdx.x * 2 + g; r < NN; r += BN_NBLK * 2) {
            float v = h[(size_t)r * COLS + c];
            s += v; q += v * v;
        }
    }
    sm[t] = s; sq[t] = q;
    __syncthreads();
    if (t < 128) {
        psum[blockIdx.x * 128 + t] = sm[t] + sm[t + 128];
        psq [blockIdx.x * 128 + t] = sq[t] + sq[t + 128];
    }
}

// stage 2: one block reduces BN_NBLK partials per channel
__global__ void k_bn_stats2(const float* __restrict__ psum, const float* __restrict__ psq,
                            float* __restrict__ sums, float* __restrict__ sqs)
{
    __shared__ float sm[1024], sq[1024];
    int t = threadIdx.x;
    int c = t & 127;
    int g = t >> 7;          // 0..7
    float s = 0.f, q = 0.f;
    for (int b = g; b < BN_NBLK; b += 8) {
        s += psum[b * 128 + c];
        q += psq [b * 128 + c];
    }
    sm[t] = s; sq[t] = q;
    __syncthreads();
    #pragma unroll
    for (int off = 512; off >= 128; off >>= 1) {
        if (t < off) { sm[t] += sm[t + off]; sq[t] += sq[t + off]; }
        __syncthreads();
    }
    if (t < 128) { sums[t] = sm[t]; sqs[t] = sq[t]; }
}

// ---------------- batchnorm apply (final layer -> d_out) ----------------
template<int COLS>
__global__ void k_bn_apply(const float* __restrict__ in, float* __restrict__ out,
                           const float* __restrict__ sums, const float* __restrict__ sqs,
                           const float* __restrict__ gamma, const float* __restrict__ beta,
                           int n)
{
    int idx = blockIdx.x * blockDim.x + threadIdx.x;
    if (idx >= n * COLS) return;
    int c = idx % COLS;
    float invn = 1.0f / (float)n;
    float mean = sums[c] * invn;
    float var  = sqs[c] * invn - mean * mean;     // biased, matches jnp var
    float sc = gamma[c] * rsqrtf(var + 1e-5f);
    float sh = beta[c] - mean * sc;
    out[idx] = in[idx] * sc + sh;
}

extern "C" void kernel_launch(void* const* d_in, const int* in_sizes, int n_in,
                              void* d_out, int out_size, void* d_ws, size_t ws_size,
                              hipStream_t stream)
{
    const float* x    = (const float*)d_in[0];
    const int*   eidx = (const int*)d_in[1];
    const float* eatt = (const float*)d_in[2];
    const float* W0   = (const float*)d_in[3];
    const float* as0  = (const float*)d_in[4];
    const float* ad0  = (const float*)d_in[5];
    const float* We0  = (const float*)d_in[6];
    const float* ae0  = (const float*)d_in[7];
    // d_in[8] = b0 : cancels through BN
    const float* W1   = (const float*)d_in[9];
    const float* as1  = (const float*)d_in[10];
    const float* ad1  = (const float*)d_in[11];
    const float* We1  = (const float*)d_in[12];
    const float* ae1  = (const float*)d_in[13];
    // d_in[14] = b1 : cancels through BN
    const float* bng  = (const float*)d_in[15];
    const float* bnb  = (const float*)d_in[16];
    const float* bnfg = (const float*)d_in[17];
    const float* bnfb = (const float*)d_in[18];

    const int N = NN, E = NE;
    const int* src = eidx;
    const int* dst = eidx + E;

    float* ws = (float*)d_ws;
    size_t off = 0;
    unsigned short* xs0b = (unsigned short*)(ws + off); off += (size_t)N * 64;   // N*128 bf16
    float* h   = ws + off;      off += (size_t)N * 128;                          // fp32; out1 aliases
    unsigned short* xs1b = (unsigned short*)(ws + off); off += (size_t)N * 56;   // N*112 bf16
    EdgePack* pack = (EdgePack*)(ws + off);             off += (size_t)E * 3;
    int*   rp   = (int*)(ws + off);     off += N + 2;
    int*   cur  = (int*)(ws + off);     off += N;
    int*   deg  = (int*)(ws + off);     off += N;
    float* als0 = ws + off;     off += N;
    float* ald0 = ws + off;     off += N;
    float* als1 = ws + off;     off += N;
    float* ald1 = ws + off;     off += N;
    float* stats = ws + off;    off += 512;
    float* ve = ws + off;       off += 16;
    int*   partial = (int*)(ws + off);  off += SCAN_NBLK;
    float* psum = ws + off;     off += BN_NBLK * 128;
    float* psq  = ws + off;     off += BN_NBLK * 128;
    float* out1 = h;            // alias: h dead after layer-1 gemm consumes it

    float* sum0 = stats;
    float* sq0  = stats + 128;
    float* sum1 = stats + 256;
    float* sq1  = stats + 384;

    // ---- init + CSR structure (ws is poisoned 0xAA before every call) ----
    k_init<<<(N + 255) / 256, 256, 0, stream>>>(deg, als0, ald0, als1, ald1, N);
    k_ve<<<1, 64, 0, stream>>>(We0, ae0, We1, ae1, ve);
    k_deg<<<(E + 255) / 256, 256, 0, stream>>>(dst, deg, E);
    k_scan1<<<SCAN_NBLK, SCAN_B, 0, stream>>>(deg, partial);
    k_scan2<<<1, SCAN_B, 0, stream>>>(partial);
    k_scan3<<<SCAN_NBLK, SCAN_B, 0, stream>>>(deg, partial, rp, cur);
    k_csr_fill<<<(E + 255) / 256, 256, 0, stream>>>(src, dst, eatt, ve, cur, pack, E);

    // ---- layer 0: 128 -> 128 ----
    k_gemm<128, false><<<N / 8, 256, 0, stream>>>(x, W0, xs0b, as0, ad0, als0, ald0,
                                                  nullptr, nullptr, nullptr, nullptr);
    k_aggregate<128, 0><<<(N + 3) / 4, 256, 0, stream>>>(rp, pack, als0, ald0, xs0b, h);
    k_bn_stats1<128><<<BN_NBLK, 256, 0, stream>>>(h, psum, psq);
    k_bn_stats2<<<1, 1024, 0, stream>>>(psum, psq, sum0, sq0);

    // ---- layer 1: 128 -> 112 (BN0+ReLU fused into A-staging) ----
    k_gemm<112, true><<<N / 8, 256, 0, stream>>>(h, W1, xs1b, as1, ad1, als1, ald1,
                                                 sum0, sq0, bng, bnb);
    k_aggregate<112, 1><<<(N + 3) / 4, 256, 0, stream>>>(rp, pack, als1, ald1, xs1b, out1);
    k_bn_stats1<112><<<BN_NBLK, 256, 0, stream>>>(out1, psum, psq);
    k_bn_stats2<<<1, 1024, 0, stream>>>(psum, psq, sum1, sq1);
    k_bn_apply<112><<<(N * 112 + 255) / 256, 256, 0, stream>>>(out1, (float*)d_out, sum1, sq1, bnfg, bnfb, N);
}

// Round 6
// 494.833 us; speedup vs baseline: 6.1927x; 1.0541x over previous
//
#include <hip/hip_runtime.h>
#include <math.h>

// GAT 2-layer: N=50000 nodes, E=800000 edges, heads=1
// dims: 128 -> 128 (BN+ReLU) -> 112 (BN)
#define NN 50000
#define NE 800000
constexpr int K_DIM = 128;
#define SCAN_B 256
#define SCAN_NBLK ((NN + SCAN_B - 1) / SCAN_B)   // 196
#define BN_NBLK 256

struct EdgePack { int s; float a0, a1; };        // 12 B, one record per edge

__device__ __forceinline__ unsigned short f2bf(float x) {
    unsigned u = __float_as_uint(x);
    u += 0x7fffu + ((u >> 16) & 1);              // round-to-nearest-even
    return (unsigned short)(u >> 16);
}
__device__ __forceinline__ float bf2f(unsigned short h) {
    return __uint_as_float(((unsigned)h) << 16);
}

// ---------------- init ----------------
__global__ void k_init(int* deg, float* als0, float* ald0, float* als1, float* ald1, int n)
{
    int idx = blockIdx.x * blockDim.x + threadIdx.x;
    if (idx < n) {
        deg[idx] = 0;
        als0[idx] = 0.f; ald0[idx] = 0.f;
        als1[idx] = 0.f; ald1[idx] = 0.f;
    }
}

// ve[0..7] = We0 @ a_edge0 ; ve[8..15] = We1 @ a_edge1   (heads=1 folding)
__global__ void k_ve(const float* We0, const float* ae0, const float* We1, const float* ae1,
                     float* ve)
{
    int j = threadIdx.x;
    if (j < 8) {
        float s = 0.f;
        for (int c = 0; c < 128; ++c) s += We0[j*128 + c] * ae0[c];
        ve[j] = s;
    } else if (j < 16) {
        int jj = j - 8;
        float s = 0.f;
        for (int c = 0; c < 112; ++c) s += We1[jj*112 + c] * ae1[c];
        ve[8 + jj] = s;
    }
}

// ---------------- CSR build ----------------
__global__ void k_deg(const int* __restrict__ dst, int* __restrict__ deg, int E_)
{
    int e = blockIdx.x * blockDim.x + threadIdx.x;
    if (e < E_) atomicAdd(&deg[dst[e]], 1);
}

__global__ void k_scan1(const int* __restrict__ deg, int* __restrict__ partial)
{
    __shared__ int sm[SCAN_B];
    int t = threadIdx.x;
    int idx = blockIdx.x * SCAN_B + t;
    sm[t] = (idx < NN) ? deg[idx] : 0;
    __syncthreads();
    #pragma unroll
    for (int off = SCAN_B / 2; off > 0; off >>= 1) {
        if (t < off) sm[t] += sm[t + off];
        __syncthreads();
    }
    if (t == 0) partial[blockIdx.x] = sm[0];
}

__global__ void k_scan2(int* __restrict__ partial)
{
    __shared__ int sm[SCAN_B];
    int t = threadIdx.x;
    int v = (t < SCAN_NBLK) ? partial[t] : 0;
    sm[t] = v;
    __syncthreads();
    #pragma unroll
    for (int off = 1; off < SCAN_B; off <<= 1) {
        int u = (t >= off) ? sm[t - off] : 0;
        __syncthreads();
        sm[t] += u;
        __syncthreads();
    }
    if (t < SCAN_NBLK) partial[t] = (t == 0) ? 0 : sm[t - 1];
}

__global__ void k_scan3(const int* __restrict__ deg, const int* __restrict__ partial,
                        int* __restrict__ rp, int* __restrict__ cur)
{
    __shared__ int sm[SCAN_B];
    int t = threadIdx.x;
    int idx = blockIdx.x * SCAN_B + t;
    int v = (idx < NN) ? deg[idx] : 0;
    sm[t] = v;
    __syncthreads();
    #pragma unroll
    for (int off = 1; off < SCAN_B; off <<= 1) {
        int u = (t >= off) ? sm[t - off] : 0;
        __syncthreads();
        sm[t] += u;
        __syncthreads();
    }
    int excl = partial[blockIdx.x] + ((t == 0) ? 0 : sm[t - 1]);
    if (idx < NN) { rp[idx] = excl; cur[idx] = excl; }
    if (idx == NN - 1) rp[NN] = excl + v;
}

// ---------------- edge pack: per-edge attention dots for BOTH layers, CSR order ----------------
__global__ void k_csr_fill(const int* __restrict__ src, const int* __restrict__ dst,
                           const float* __restrict__ eatt, const float* __restrict__ ve,
                           int* __restrict__ cur, EdgePack* __restrict__ pack, int E_)
{
    int e = blockIdx.x * blockDim.x + threadIdx.x;
    if (e >= E_) return;
    const float4* ea = reinterpret_cast<const float4*>(eatt + (size_t)e * 8);
    float4 e0 = ea[0], e1 = ea[1];
    float a0 = e0.x * ve[0] + e0.y * ve[1] + e0.z * ve[2] + e0.w * ve[3]
             + e1.x * ve[4] + e1.y * ve[5] + e1.z * ve[6] + e1.w * ve[7];
    float a1 = e0.x * ve[8] + e0.y * ve[9] + e0.z * ve[10] + e0.w * ve[11]
             + e1.x * ve[12] + e1.y * ve[13] + e1.z * ve[14] + e1.w * ve[15];
    int d = dst[e];
    int pos = atomicAdd(&cur[d], 1);
    EdgePack p; p.s = src[e]; p.a0 = a0; p.a1 = a1;
    pack[pos] = p;
}

// ---------------- node GEMM: bf16 out + fused attention-dot epilogue ----------------
// BN_IN: apply batchnorm+relu (from sums/sqs) to A rows while staging into LDS.
template<int COLS, bool BN_IN>
__global__ void k_gemm(const float* __restrict__ A, const float* __restrict__ W,
                       unsigned short* __restrict__ out,
                       const float* __restrict__ a_src, const float* __restrict__ a_dst,
                       float* __restrict__ als, float* __restrict__ ald,
                       const float* __restrict__ bsum, const float* __restrict__ bsq,
                       const float* __restrict__ gamma, const float* __restrict__ beta)
{
    __shared__ float Xl[8 * K_DIM];     // 8 rows of A
    __shared__ float scN[K_DIM], shN[K_DIM];
    int c = threadIdx.x & 127;
    int g = threadIdx.x >> 7;           // 0..1 -> rows g*4 .. g*4+3
    int lane = threadIdx.x & 63;
    int rb = blockIdx.x * 8;            // grid is exactly NN/8

    if (BN_IN) {
        if (threadIdx.x < K_DIM) {
            int k = threadIdx.x;
            float invn = 1.0f / (float)NN;
            float mean = bsum[k] * invn;
            float var  = bsq[k] * invn - mean * mean;
            float sc = gamma[k] * rsqrtf(var + 1e-5f);
            scN[k] = sc;
            shN[k] = beta[k] - mean * sc;
        }
        __syncthreads();
    }

    for (int i = threadIdx.x; i < 8 * K_DIM; i += blockDim.x) {
        int r = rb + (i >> 7);
        int k = i & 127;
        float v = A[(size_t)r * K_DIM + k];
        if (BN_IN) v = fmaxf(v * scN[k] + shN[k], 0.f);
        Xl[i] = v;
    }
    __syncthreads();

    int cc = (c < COLS) ? c : 0;        // clamp to stay in-bounds for W
    float acc0 = 0.f, acc1 = 0.f, acc2 = 0.f, acc3 = 0.f;
    const float* xb = &Xl[g * 4 * K_DIM];
    #pragma unroll 8
    for (int k = 0; k < K_DIM; ++k) {
        float w = W[k * COLS + cc];
        acc0 += xb[0 * K_DIM + k] * w;
        acc1 += xb[1 * K_DIM + k] * w;
        acc2 += xb[2 * K_DIM + k] * w;
        acc3 += xb[3 * K_DIM + k] * w;
    }
    int r0 = rb + g * 4;
    if (c < COLS) {
        out[(size_t)(r0 + 0) * COLS + c] = f2bf(acc0);
        out[(size_t)(r0 + 1) * COLS + c] = f2bf(acc1);
        out[(size_t)(r0 + 2) * COLS + c] = f2bf(acc2);
        out[(size_t)(r0 + 3) * COLS + c] = f2bf(acc3);
    }
    // fused attention dots (fp32 accs): mask inactive cols with 0 weight
    float asv = (c < COLS) ? a_src[c] : 0.f;
    float adv = (c < COLS) ? a_dst[c] : 0.f;
    float p0 = acc0 * asv, p1 = acc1 * asv, p2 = acc2 * asv, p3 = acc3 * asv;
    float q0 = acc0 * adv, q1 = acc1 * adv, q2 = acc2 * adv, q3 = acc3 * adv;
    #pragma unroll
    for (int off = 32; off > 0; off >>= 1) {
        p0 += __shfl_down(p0, off); p1 += __shfl_down(p1, off);
        p2 += __shfl_down(p2, off); p3 += __shfl_down(p3, off);
        q0 += __shfl_down(q0, off); q1 += __shfl_down(q1, off);
        q2 += __shfl_down(q2, off); q3 += __shfl_down(q3, off);
    }
    if (lane == 0) {
        unsafeAtomicAdd(&als[r0 + 0], p0); unsafeAtomicAdd(&als[r0 + 1], p1);
        unsafeAtomicAdd(&als[r0 + 2], p2); unsafeAtomicAdd(&als[r0 + 3], p3);
        unsafeAtomicAdd(&ald[r0 + 0], q0); unsafeAtomicAdd(&ald[r0 + 1], q1);
        unsafeAtomicAdd(&ald[r0 + 2], q2); unsafeAtomicAdd(&ald[r0 + 3], q3);
    }
}

// ---------------- per-dst aggregate: one wave per node, half-wave edge split ----------------
// lanes 0-31 = edge A, lanes 32-63 = edge B; each lane loads ushort4 (4 cols).
// unroll x2 -> 4 independent row gathers in flight.
template<int COLS, int LAYER>
__global__ void k_aggregate(const int* __restrict__ rp, const EdgePack* __restrict__ pack,
                            const float* __restrict__ als, const float* __restrict__ ald,
                            const unsigned short* __restrict__ xs, float* __restrict__ out)
{
    int w = blockIdx.x * 4 + (threadIdx.x >> 6);
    int lane = threadIdx.x & 63;
    if (w >= NN) return;
    int beg = rp[w], end = rp[w + 1];
    float aldv = ald[w];
    int half = lane >> 5;            // 0: edge A, 1: edge B
    int hl = lane & 31;
    int col = hl * 4;
    bool act = (col < COLS);

    float acc0 = 0.f, acc1 = 0.f, acc2 = 0.f, acc3 = 0.f, den = 0.f;
    int j = beg;
    for (; j + 4 <= end; j += 4) {
        EdgePack p0 = pack[j + half];
        EdgePack p1 = pack[j + 2 + half];
        float a0 = als[p0.s] + aldv + (LAYER ? p0.a1 : p0.a0);
        float a1 = als[p1.s] + aldv + (LAYER ? p1.a1 : p1.a0);
        a0 = a0 > 0.f ? a0 : 0.2f * a0;
        a1 = a1 > 0.f ? a1 : 0.2f * a1;
        float ex0 = __expf(a0), ex1 = __expf(a1);
        den += ex0 + ex1;
        if (act) {
            ushort4 u0 = *reinterpret_cast<const ushort4*>(xs + (size_t)p0.s * COLS + col);
            ushort4 u1 = *reinterpret_cast<const ushort4*>(xs + (size_t)p1.s * COLS + col);
            acc0 += ex0 * bf2f(u0.x) + ex1 * bf2f(u1.x);
            acc1 += ex0 * bf2f(u0.y) + ex1 * bf2f(u1.y);
            acc2 += ex0 * bf2f(u0.z) + ex1 * bf2f(u1.z);
            acc3 += ex0 * bf2f(u0.w) + ex1 * bf2f(u1.w);
        }
    }
    for (; j < end; j += 2) {
        int jj = j + half;
        if (jj < end) {
            EdgePack p = pack[jj];
            float a = als[p.s] + aldv + (LAYER ? p.a1 : p.a0);
            a = a > 0.f ? a : 0.2f * a;
            float ex = __expf(a);
            den += ex;
            if (act) {
                ushort4 u = *reinterpret_cast<const ushort4*>(xs + (size_t)p.s * COLS + col);
                acc0 += ex * bf2f(u.x); acc1 += ex * bf2f(u.y);
                acc2 += ex * bf2f(u.z); acc3 += ex * bf2f(u.w);
            }
        }
    }
    // fold the two half-waves (lane L and L^32 hold the same columns)
    acc0 += __shfl_xor(acc0, 32);
    acc1 += __shfl_xor(acc1, 32);
    acc2 += __shfl_xor(acc2, 32);
    acc3 += __shfl_xor(acc3, 32);
    den  += __shfl_xor(den, 32);
    float inv = (end > beg) ? 1.f / den : 0.f;
    if (half == 0 && act) {
        float4 o; o.x = acc0 * inv; o.y = acc1 * inv; o.z = acc2 * inv; o.w = acc3 * inv;
        *reinterpret_cast<float4*>(out + (size_t)w * COLS + col) = o;
    }
}

// ---------------- batchnorm stats, stage 1: per-block partials (no atomics) ----------------
template<int COLS>
__global__ void k_bn_stats1(const float* __restrict__ h, float* __restrict__ psum,
                            float* __restrict__ psq)
{
    __shared__ float sm[256], sq[256];
    int t = threadIdx.x;
    int c = t & 127;
    int g = t >> 7;
    float s = 0.f, q = 0.f;
    if (c < COLS) {
        for (int r = blockIdx.x * 2 + g; r < NN; r += BN_NBLK * 2) {
            float v = h[(size_t)r * COLS + c];
            s += v; q += v * v;
        }
    }
    sm[t] = s; sq[t] = q;
    __syncthreads();
    if (t < 128) {
        psum[blockIdx.x * 128 + t] = sm[t] + sm[t + 128];
        psq [blockIdx.x * 128 + t] = sq[t] + sq[t + 128];
    }
}

// stage 2: one block reduces BN_NBLK partials per channel
__global__ void k_bn_stats2(const float* __restrict__ psum, const float* __restrict__ psq,
                            float* __restrict__ sums, float* __restrict__ sqs)
{
    __shared__ float sm[1024], sq[1024];
    int t = threadIdx.x;
    int c = t & 127;
    int g = t >> 7;          // 0..7
    float s = 0.f, q = 0.f;
    for (int b = g; b < BN_NBLK; b += 8) {
        s += psum[b * 128 + c];
        q += psq [b * 128 + c];
    }
    sm[t] = s; sq[t] = q;
    __syncthreads();
    #pragma unroll
    for (int off = 512; off >= 128; off >>= 1) {
        if (t < off) { sm[t] += sm[t + off]; sq[t] += sq[t + off]; }
        __syncthreads();
    }
    if (t < 128) { sums[t] = sm[t]; sqs[t] = sq[t]; }
}

// ---------------- batchnorm apply (final layer -> d_out) ----------------
template<int COLS>
__global__ void k_bn_apply(const float* __restrict__ in, float* __restrict__ out,
                           const float* __restrict__ sums, const float* __restrict__ sqs,
                           const float* __restrict__ gamma, const float* __restrict__ beta,
                           int n)
{
    int idx = blockIdx.x * blockDim.x + threadIdx.x;
    if (idx >= n * COLS) return;
    int c = idx % COLS;
    float invn = 1.0f / (float)n;
    float mean = sums[c] * invn;
    float var  = sqs[c] * invn - mean * mean;     // biased, matches jnp var
    float sc = gamma[c] * rsqrtf(var + 1e-5f);
    float sh = beta[c] - mean * sc;
    out[idx] = in[idx] * sc + sh;
}

extern "C" void kernel_launch(void* const* d_in, const int* in_sizes, int n_in,
                              void* d_out, int out_size, void* d_ws, size_t ws_size,
                              hipStream_t stream)
{
    const float* x    = (const float*)d_in[0];
    const int*   eidx = (const int*)d_in[1];
    const float* eatt = (const float*)d_in[2];
    const float* W0   = (const float*)d_in[3];
    const float* as0  = (const float*)d_in[4];
    const float* ad0  = (const float*)d_in[5];
    const float* We0  = (const float*)d_in[6];
    const float* ae0  = (const float*)d_in[7];
    // d_in[8] = b0 : cancels through BN
    const float* W1   = (const float*)d_in[9];
    const float* as1  = (const float*)d_in[10];
    const float* ad1  = (const float*)d_in[11];
    const float* We1  = (const float*)d_in[12];
    const float* ae1  = (const float*)d_in[13];
    // d_in[14] = b1 : cancels through BN
    const float* bng  = (const float*)d_in[15];
    const float* bnb  = (const float*)d_in[16];
    const float* bnfg = (const float*)d_in[17];
    const float* bnfb = (const float*)d_in[18];

    const int N = NN, E = NE;
    const int* src = eidx;
    const int* dst = eidx + E;

    float* ws = (float*)d_ws;
    size_t off = 0;
    unsigned short* xs0b = (unsigned short*)(ws + off); off += (size_t)N * 64;   // N*128 bf16
    float* h   = ws + off;      off += (size_t)N * 128;                          // fp32; out1 aliases
    unsigned short* xs1b = (unsigned short*)(ws + off); off += (size_t)N * 56;   // N*112 bf16
    EdgePack* pack = (EdgePack*)(ws + off);             off += (size_t)E * 3;
    int*   rp   = (int*)(ws + off);     off += N + 2;
    int*   cur  = (int*)(ws + off);     off += N;
    int*   deg  = (int*)(ws + off);     off += N;
    float* als0 = ws + off;     off += N;
    float* ald0 = ws + off;     off += N;
    float* als1 = ws + off;     off += N;
    float* ald1 = ws + off;     off += N;
    float* stats = ws + off;    off += 512;
    float* ve = ws + off;       off += 16;
    int*   partial = (int*)(ws + off);  off += SCAN_NBLK;
    float* psum = ws + off;     off += BN_NBLK * 128;
    float* psq  = ws + off;     off += BN_NBLK * 128;
    float* out1 = h;            // alias: h dead after layer-1 gemm consumes it

    float* sum0 = stats;
    float* sq0  = stats + 128;
    float* sum1 = stats + 256;
    float* sq1  = stats + 384;

    // ---- init + CSR structure (ws is poisoned 0xAA before every call) ----
    k_init<<<(N + 255) / 256, 256, 0, stream>>>(deg, als0, ald0, als1, ald1, N);
    k_ve<<<1, 64, 0, stream>>>(We0, ae0, We1, ae1, ve);
    k_deg<<<(E + 255) / 256, 256, 0, stream>>>(dst, deg, E);
    k_scan1<<<SCAN_NBLK, SCAN_B, 0, stream>>>(deg, partial);
    k_scan2<<<1, SCAN_B, 0, stream>>>(partial);
    k_scan3<<<SCAN_NBLK, SCAN_B, 0, stream>>>(deg, partial, rp, cur);
    k_csr_fill<<<(E + 255) / 256, 256, 0, stream>>>(src, dst, eatt, ve, cur, pack, E);

    // ---- layer 0: 128 -> 128 ----
    k_gemm<128, false><<<N / 8, 256, 0, stream>>>(x, W0, xs0b, as0, ad0, als0, ald0,
                                                  nullptr, nullptr, nullptr, nullptr);
    k_aggregate<128, 0><<<(N + 3) / 4, 256, 0, stream>>>(rp, pack, als0, ald0, xs0b, h);
    k_bn_stats1<128><<<BN_NBLK, 256, 0, stream>>>(h, psum, psq);
    k_bn_stats2<<<1, 1024, 0, stream>>>(psum, psq, sum0, sq0);

    // ---- layer 1: 128 -> 112 (BN0+ReLU fused into A-staging) ----
    k_gemm<112, true><<<N / 8, 256, 0, stream>>>(h, W1, xs1b, as1, ad1, als1, ald1,
                                                 sum0, sq0, bng, bnb);
    k_aggregate<112, 1><<<(N + 3) / 4, 256, 0, stream>>>(rp, pack, als1, ald1, xs1b, out1);
    k_bn_stats1<112><<<BN_NBLK, 256, 0, stream>>>(out1, psum, psq);
    k_bn_stats2<<<1, 1024, 0, stream>>>(psum, psq, sum1, sq1);
    k_bn_apply<112><<<(N * 112 + 255) / 256, 256, 0, stream>>>(out1, (float*)d_out, sum1, sq1, bnfg, bnfb, N);
}

// Round 7
// 481.629 us; speedup vs baseline: 6.3625x; 1.0274x over previous
//
#include <hip/hip_runtime.h>
#include <math.h>

// GAT 2-layer: N=50000 nodes, E=800000 edges, heads=1
// dims: 128 -> 128 (BN+ReLU) -> 112 (BN)
#define NN 50000
#define NPAD 50048               // 782 * 64, zero-padded rows for MFMA tiles
#define NE 800000
constexpr int K_DIM = 128;
#define SCAN_B 256
#define SCAN_NBLK ((NN + SCAN_B - 1) / SCAN_B)   // 196
#define BN_NBLK 256

struct EdgePack { int s; float a0, a1; };        // 12 B, one record per edge

typedef __attribute__((ext_vector_type(8))) short bf16x8;   // 4 VGPRs: MFMA A/B frag
typedef __attribute__((ext_vector_type(4))) float f32x4;    // MFMA C/D frag

__device__ __forceinline__ unsigned short f2bf(float x) {
    unsigned u = __float_as_uint(x);
    u += 0x7fffu + ((u >> 16) & 1);              // round-to-nearest-even
    return (unsigned short)(u >> 16);
}
__device__ __forceinline__ float bf2f(unsigned short h) {
    return __uint_as_float(((unsigned)h) << 16);
}

// ---------------- init ----------------
__global__ void k_init(int* deg, int n)
{
    int idx = blockIdx.x * blockDim.x + threadIdx.x;
    if (idx < n) deg[idx] = 0;
}

// ve[0..7] = We0 @ a_edge0 ; ve[8..15] = We1 @ a_edge1   (heads=1 folding)
__global__ void k_ve(const float* We0, const float* ae0, const float* We1, const float* ae1,
                     float* ve)
{
    int j = threadIdx.x;
    if (j < 8) {
        float s = 0.f;
        for (int c = 0; c < 128; ++c) s += We0[j*128 + c] * ae0[c];
        ve[j] = s;
    } else if (j < 16) {
        int jj = j - 8;
        float s = 0.f;
        for (int c = 0; c < 112; ++c) s += We1[jj*112 + c] * ae1[c];
        ve[8 + jj] = s;
    }
}

// ---------------- CSR build ----------------
__global__ void k_deg(const int* __restrict__ dst, int* __restrict__ deg, int E_)
{
    int e = blockIdx.x * blockDim.x + threadIdx.x;
    if (e < E_) atomicAdd(&deg[dst[e]], 1);
}

__global__ void k_scan1(const int* __restrict__ deg, int* __restrict__ partial)
{
    __shared__ int sm[SCAN_B];
    int t = threadIdx.x;
    int idx = blockIdx.x * SCAN_B + t;
    sm[t] = (idx < NN) ? deg[idx] : 0;
    __syncthreads();
    #pragma unroll
    for (int off = SCAN_B / 2; off > 0; off >>= 1) {
        if (t < off) sm[t] += sm[t + off];
        __syncthreads();
    }
    if (t == 0) partial[blockIdx.x] = sm[0];
}

__global__ void k_scan2(int* __restrict__ partial)
{
    __shared__ int sm[SCAN_B];
    int t = threadIdx.x;
    int v = (t < SCAN_NBLK) ? partial[t] : 0;
    sm[t] = v;
    __syncthreads();
    #pragma unroll
    for (int off = 1; off < SCAN_B; off <<= 1) {
        int u = (t >= off) ? sm[t - off] : 0;
        __syncthreads();
        sm[t] += u;
        __syncthreads();
    }
    if (t < SCAN_NBLK) partial[t] = (t == 0) ? 0 : sm[t - 1];
}

__global__ void k_scan3(const int* __restrict__ deg, const int* __restrict__ partial,
                        int* __restrict__ rp, int* __restrict__ cur)
{
    __shared__ int sm[SCAN_B];
    int t = threadIdx.x;
    int idx = blockIdx.x * SCAN_B + t;
    int v = (idx < NN) ? deg[idx] : 0;
    sm[t] = v;
    __syncthreads();
    #pragma unroll
    for (int off = 1; off < SCAN_B; off <<= 1) {
        int u = (t >= off) ? sm[t - off] : 0;
        __syncthreads();
        sm[t] += u;
        __syncthreads();
    }
    int excl = partial[blockIdx.x] + ((t == 0) ? 0 : sm[t - 1]);
    if (idx < NN) { rp[idx] = excl; cur[idx] = excl; }
    if (idx == NN - 1) rp[NN] = excl + v;
}

// ---------------- edge pack: per-edge attention dots for BOTH layers, CSR order ----------------
__global__ void k_csr_fill(const int* __restrict__ src, const int* __restrict__ dst,
                           const float* __restrict__ eatt, const float* __restrict__ ve,
                           int* __restrict__ cur, EdgePack* __restrict__ pack, int E_)
{
    int e = blockIdx.x * blockDim.x + threadIdx.x;
    if (e >= E_) return;
    const float4* ea = reinterpret_cast<const float4*>(eatt + (size_t)e * 8);
    float4 e0 = ea[0], e1 = ea[1];
    float a0 = e0.x * ve[0] + e0.y * ve[1] + e0.z * ve[2] + e0.w * ve[3]
             + e1.x * ve[4] + e1.y * ve[5] + e1.z * ve[6] + e1.w * ve[7];
    float a1 = e0.x * ve[8] + e0.y * ve[9] + e0.z * ve[10] + e0.w * ve[11]
             + e1.x * ve[12] + e1.y * ve[13] + e1.z * ve[14] + e1.w * ve[15];
    int d = dst[e];
    int pos = atomicAdd(&cur[d], 1);
    EdgePack p; p.s = src[e]; p.a0 = a0; p.a1 = a1;
    pack[pos] = p;
}

// ---------------- fp32 -> split bf16 (Ah + Al), zero-padded rows ----------------
__global__ void k_cvt_x(const float* __restrict__ x, unsigned short* __restrict__ Ah,
                        unsigned short* __restrict__ Al)
{
    int idx = blockIdx.x * 256 + threadIdx.x;    // float4 granularity: NPAD*32
    int r = idx >> 5;
    float4 v = (r < NN) ? reinterpret_cast<const float4*>(x)[idx]
                        : make_float4(0.f, 0.f, 0.f, 0.f);
    ushort4 hi, lo;
    hi.x = f2bf(v.x); lo.x = f2bf(v.x - bf2f(hi.x));
    hi.y = f2bf(v.y); lo.y = f2bf(v.y - bf2f(hi.y));
    hi.z = f2bf(v.z); lo.z = f2bf(v.z - bf2f(hi.z));
    hi.w = f2bf(v.w); lo.w = f2bf(v.w - bf2f(hi.w));
    reinterpret_cast<ushort4*>(Ah)[idx] = hi;
    reinterpret_cast<ushort4*>(Al)[idx] = lo;
}

// ---------------- BN + ReLU + split bf16 (layer-1 operand) ----------------
__global__ void k_bn_cvt(const float* __restrict__ h, unsigned short* __restrict__ Hh,
                         unsigned short* __restrict__ Hl,
                         const float* __restrict__ sums, const float* __restrict__ sqs,
                         const float* __restrict__ gamma, const float* __restrict__ beta)
{
    __shared__ float scN[128], shN[128];
    if (threadIdx.x < 128) {
        int k = threadIdx.x;
        float invn = 1.0f / (float)NN;
        float mean = sums[k] * invn;
        float var  = sqs[k] * invn - mean * mean;
        float sc = gamma[k] * rsqrtf(var + 1e-5f);
        scN[k] = sc;
        shN[k] = beta[k] - mean * sc;
    }
    __syncthreads();
    int idx = blockIdx.x * 256 + threadIdx.x;    // float4 granularity: NPAD*32
    int r = idx >> 5;
    int c4 = (idx & 31) * 4;
    float4 v = make_float4(0.f, 0.f, 0.f, 0.f);
    if (r < NN) {
        v = reinterpret_cast<const float4*>(h)[idx];
        v.x = fmaxf(v.x * scN[c4 + 0] + shN[c4 + 0], 0.f);
        v.y = fmaxf(v.y * scN[c4 + 1] + shN[c4 + 1], 0.f);
        v.z = fmaxf(v.z * scN[c4 + 2] + shN[c4 + 2], 0.f);
        v.w = fmaxf(v.w * scN[c4 + 3] + shN[c4 + 3], 0.f);
    }
    ushort4 hi, lo;
    hi.x = f2bf(v.x); lo.x = f2bf(v.x - bf2f(hi.x));
    hi.y = f2bf(v.y); lo.y = f2bf(v.y - bf2f(hi.y));
    hi.z = f2bf(v.z); lo.z = f2bf(v.z - bf2f(hi.z));
    hi.w = f2bf(v.w); lo.w = f2bf(v.w - bf2f(hi.w));
    reinterpret_cast<ushort4*>(Hh)[idx] = hi;
    reinterpret_cast<ushort4*>(Hl)[idx] = lo;
}

// ---------------- W [128][COLS] fp32 -> transposed split bf16 Wt[c][k] ----------------
template<int COLS>
__global__ void k_cvt_w(const float* __restrict__ W, unsigned short* __restrict__ Wth,
                        unsigned short* __restrict__ Wtl)
{
    int idx = blockIdx.x * 256 + threadIdx.x;
    if (idx >= 128 * COLS) return;
    int k = idx / COLS, c = idx % COLS;
    float v = W[idx];
    unsigned short hi = f2bf(v);
    unsigned short lo = f2bf(v - bf2f(hi));
    Wth[c * 128 + k] = hi;
    Wtl[c * 128 + k] = lo;
}

// ---------------- MFMA GEMM: one wave = 16 rows x COLS, bf16x3 split precision ----------------
// out bf16 [NN][COLS]; als/ald = attention dots (full-K in wave -> direct store, no atomics)
template<int COLS>
__global__ void k_gemm_mfma(const unsigned short* __restrict__ Ah,
                            const unsigned short* __restrict__ Al,
                            const unsigned short* __restrict__ Wth,
                            const unsigned short* __restrict__ Wtl,
                            unsigned short* __restrict__ out,
                            const float* __restrict__ a_src, const float* __restrict__ a_dst,
                            float* __restrict__ als, float* __restrict__ ald)
{
    constexpr int NT = COLS / 16;
    int wv = threadIdx.x >> 6;
    int lane = threadIdx.x & 63;
    int r0 = blockIdx.x * 64 + wv * 16;
    int m = lane & 15;
    int quad = lane >> 4;

    const unsigned short* pah = Ah + (size_t)(r0 + m) * 128 + quad * 8;
    const unsigned short* pal = Al + (size_t)(r0 + m) * 128 + quad * 8;

    f32x4 acc[NT];
    #pragma unroll
    for (int t = 0; t < NT; ++t) acc[t] = f32x4{0.f, 0.f, 0.f, 0.f};

    #pragma unroll
    for (int ks = 0; ks < 4; ++ks) {
        bf16x8 ah = *reinterpret_cast<const bf16x8*>(pah + ks * 32);
        bf16x8 al = *reinterpret_cast<const bf16x8*>(pal + ks * 32);
        #pragma unroll
        for (int t = 0; t < NT; ++t) {
            size_t boff = (size_t)(t * 16 + m) * 128 + ks * 32 + quad * 8;
            bf16x8 bh = *reinterpret_cast<const bf16x8*>(Wth + boff);
            bf16x8 bl = *reinterpret_cast<const bf16x8*>(Wtl + boff);
            acc[t] = __builtin_amdgcn_mfma_f32_16x16x32_bf16(ah, bh, acc[t], 0, 0, 0);
            acc[t] = __builtin_amdgcn_mfma_f32_16x16x32_bf16(al, bh, acc[t], 0, 0, 0);
            acc[t] = __builtin_amdgcn_mfma_f32_16x16x32_bf16(ah, bl, acc[t], 0, 0, 0);
        }
    }

    // epilogue: bf16 store + fused attention dots (C/D: col=lane&15, row=quad*4+reg)
    float p[4] = {0.f, 0.f, 0.f, 0.f}, q[4] = {0.f, 0.f, 0.f, 0.f};
    #pragma unroll
    for (int t = 0; t < NT; ++t) {
        int c = t * 16 + m;
        float asv = a_src[c], adv = a_dst[c];
        #pragma unroll
        for (int rI = 0; rI < 4; ++rI) {
            float v = acc[t][rI];
            int row = r0 + quad * 4 + rI;
            if (row < NN) out[(size_t)row * COLS + c] = f2bf(v);
            p[rI] += v * asv;
            q[rI] += v * adv;
        }
    }
    #pragma unroll
    for (int rI = 0; rI < 4; ++rI) {
        #pragma unroll
        for (int off = 1; off <= 8; off <<= 1) {
            p[rI] += __shfl_xor(p[rI], off);
            q[rI] += __shfl_xor(q[rI], off);
        }
    }
    if (m == 0) {
        #pragma unroll
        for (int rI = 0; rI < 4; ++rI) {
            int row = r0 + quad * 4 + rI;
            if (row < NN) { als[row] = p[rI]; ald[row] = q[rI]; }
        }
    }
}

// ---------------- per-dst aggregate: one wave per node, half-wave edge split ----------------
template<int COLS, int LAYER>
__global__ void k_aggregate(const int* __restrict__ rp, const EdgePack* __restrict__ pack,
                            const float* __restrict__ als, const float* __restrict__ ald,
                            const unsigned short* __restrict__ xs, float* __restrict__ out)
{
    int w = blockIdx.x * 4 + (threadIdx.x >> 6);
    int lane = threadIdx.x & 63;
    if (w >= NN) return;
    int beg = rp[w], end = rp[w + 1];
    float aldv = ald[w];
    int half = lane >> 5;            // 0: edge A, 1: edge B
    int hl = lane & 31;
    int col = hl * 4;
    bool act = (col < COLS);

    float acc0 = 0.f, acc1 = 0.f, acc2 = 0.f, acc3 = 0.f, den = 0.f;
    int j = beg;
    for (; j + 4 <= end; j += 4) {
        EdgePack p0 = pack[j + half];
        EdgePack p1 = pack[j + 2 + half];
        float a0 = als[p0.s] + aldv + (LAYER ? p0.a1 : p0.a0);
        float a1 = als[p1.s] + aldv + (LAYER ? p1.a1 : p1.a0);
        a0 = a0 > 0.f ? a0 : 0.2f * a0;
        a1 = a1 > 0.f ? a1 : 0.2f * a1;
        float ex0 = __expf(a0), ex1 = __expf(a1);
        den += ex0 + ex1;
        if (act) {
            ushort4 u0 = *reinterpret_cast<const ushort4*>(xs + (size_t)p0.s * COLS + col);
            ushort4 u1 = *reinterpret_cast<const ushort4*>(xs + (size_t)p1.s * COLS + col);
            acc0 += ex0 * bf2f(u0.x) + ex1 * bf2f(u1.x);
            acc1 += ex0 * bf2f(u0.y) + ex1 * bf2f(u1.y);
            acc2 += ex0 * bf2f(u0.z) + ex1 * bf2f(u1.z);
            acc3 += ex0 * bf2f(u0.w) + ex1 * bf2f(u1.w);
        }
    }
    for (; j < end; j += 2) {
        int jj = j + half;
        if (jj < end) {
            EdgePack p = pack[jj];
            float a = als[p.s] + aldv + (LAYER ? p.a1 : p.a0);
            a = a > 0.f ? a : 0.2f * a;
            float ex = __expf(a);
            den += ex;
            if (act) {
                ushort4 u = *reinterpret_cast<const ushort4*>(xs + (size_t)p.s * COLS + col);
                acc0 += ex * bf2f(u.x); acc1 += ex * bf2f(u.y);
                acc2 += ex * bf2f(u.z); acc3 += ex * bf2f(u.w);
            }
        }
    }
    acc0 += __shfl_xor(acc0, 32);
    acc1 += __shfl_xor(acc1, 32);
    acc2 += __shfl_xor(acc2, 32);
    acc3 += __shfl_xor(acc3, 32);
    den  += __shfl_xor(den, 32);
    float inv = (end > beg) ? 1.f / den : 0.f;
    if (half == 0 && act) {
        float4 o; o.x = acc0 * inv; o.y = acc1 * inv; o.z = acc2 * inv; o.w = acc3 * inv;
        *reinterpret_cast<float4*>(out + (size_t)w * COLS + col) = o;
    }
}

// ---------------- batchnorm stats, stage 1: per-block partials (no atomics) ----------------
template<int COLS>
__global__ void k_bn_stats1(const float* __restrict__ h, float* __restrict__ psum,
                            float* __restrict__ psq)
{
    __shared__ float sm[256], sq[256];
    int t = threadIdx.x;
    int c = t & 127;
    int g = t >> 7;
    float s = 0.f, q = 0.f;
    if (c < COLS) {
        for (int r = blockIdx.x * 2 + g; r < NN; r += BN_NBLK * 2) {
            float v = h[(size_t)r * COLS + c];
            s += v; q += v * v;
        }
    }
    sm[t] = s; sq[t] = q;
    __syncthreads();
    if (t < 128) {
        psum[blockIdx.x * 128 + t] = sm[t] + sm[t + 128];
        psq [blockIdx.x * 128 + t] = sq[t] + sq[t + 128];
    }
}

// stage 2: one block reduces BN_NBLK partials per channel
__global__ void k_bn_stats2(const float* __restrict__ psum, const float* __restrict__ psq,
                            float* __restrict__ sums, float* __restrict__ sqs)
{
    __shared__ float sm[1024], sq[1024];
    int t = threadIdx.x;
    int c = t & 127;
    int g = t >> 7;          // 0..7
    float s = 0.f, q = 0.f;
    for (int b = g; b < BN_NBLK; b += 8) {
        s += psum[b * 128 + c];
        q += psq [b * 128 + c];
    }
    sm[t] = s; sq[t] = q;
    __syncthreads();
    #pragma unroll
    for (int off = 512; off >= 128; off >>= 1) {
        if (t < off) { sm[t] += sm[t + off]; sq[t] += sq[t + off]; }
        __syncthreads();
    }
    if (t < 128) { sums[t] = sm[t]; sqs[t] = sq[t]; }
}

// ---------------- batchnorm apply (final layer -> d_out) ----------------
template<int COLS>
__global__ void k_bn_apply(const float* __restrict__ in, float* __restrict__ out,
                           const float* __restrict__ sums, const float* __restrict__ sqs,
                           const float* __restrict__ gamma, const float* __restrict__ beta,
                           int n)
{
    int idx = blockIdx.x * blockDim.x + threadIdx.x;
    if (idx >= n * COLS) return;
    int c = idx % COLS;
    float invn = 1.0f / (float)n;
    float mean = sums[c] * invn;
    float var  = sqs[c] * invn - mean * mean;     // biased, matches jnp var
    float sc = gamma[c] * rsqrtf(var + 1e-5f);
    float sh = beta[c] - mean * sc;
    out[idx] = in[idx] * sc + sh;
}

extern "C" void kernel_launch(void* const* d_in, const int* in_sizes, int n_in,
                              void* d_out, int out_size, void* d_ws, size_t ws_size,
                              hipStream_t stream)
{
    const float* x    = (const float*)d_in[0];
    const int*   eidx = (const int*)d_in[1];
    const float* eatt = (const float*)d_in[2];
    const float* W0   = (const float*)d_in[3];
    const float* as0  = (const float*)d_in[4];
    const float* ad0  = (const float*)d_in[5];
    const float* We0  = (const float*)d_in[6];
    const float* ae0  = (const float*)d_in[7];
    // d_in[8] = b0 : cancels through BN
    const float* W1   = (const float*)d_in[9];
    const float* as1  = (const float*)d_in[10];
    const float* ad1  = (const float*)d_in[11];
    const float* We1  = (const float*)d_in[12];
    const float* ae1  = (const float*)d_in[13];
    // d_in[14] = b1 : cancels through BN
    const float* bng  = (const float*)d_in[15];
    const float* bnb  = (const float*)d_in[16];
    const float* bnfg = (const float*)d_in[17];
    const float* bnfb = (const float*)d_in[18];

    const int N = NN, E = NE;
    const int* src = eidx;
    const int* dst = eidx + E;

    float* ws = (float*)d_ws;
    size_t off = 0;
    unsigned short* xs0b = (unsigned short*)(ws + off); off += (size_t)N * 64;   // N*128 bf16
    float* h   = ws + off;      off += (size_t)N * 128;                          // fp32; out1 aliases
    unsigned short* xs1b = (unsigned short*)(ws + off); off += (size_t)N * 56;   // N*112 bf16
    EdgePack* pack = (EdgePack*)(ws + off);             off += (size_t)E * 3;
    unsigned short* Ah = (unsigned short*)(ws + off);   off += (size_t)NPAD * 64; // split operand hi
    unsigned short* Al = (unsigned short*)(ws + off);   off += (size_t)NPAD * 64; // split operand lo
    int*   rp   = (int*)(ws + off);     off += N + 2;
    int*   cur  = (int*)(ws + off);     off += N;
    int*   deg  = (int*)(ws + off);     off += N;
    float* als0 = ws + off;     off += N;
    float* ald0 = ws + off;     off += N;
    float* als1 = ws + off;     off += N;
    float* ald1 = ws + off;     off += N;
    float* stats = ws + off;    off += 512;
    float* ve = ws + off;       off += 16;
    int*   partial = (int*)(ws + off);  off += SCAN_NBLK;
    float* psum = ws + off;     off += BN_NBLK * 128;
    float* psq  = ws + off;     off += BN_NBLK * 128;
    unsigned short* Wth0 = (unsigned short*)(ws + off); off += 128 * 64;         // 128x128 bf16
    unsigned short* Wtl0 = (unsigned short*)(ws + off); off += 128 * 64;
    unsigned short* Wth1 = (unsigned short*)(ws + off); off += 112 * 64;         // 112x128 bf16
    unsigned short* Wtl1 = (unsigned short*)(ws + off); off += 112 * 64;
    float* out1 = h;                       // alias: h dead after k_bn_cvt consumes it
    unsigned short* Hh = Ah;               // alias: Ah/Al dead after layer-0 gemm
    unsigned short* Hl = Al;

    float* sum0 = stats;
    float* sq0  = stats + 128;
    float* sum1 = stats + 256;
    float* sq1  = stats + 384;

    // ---- init + CSR structure (ws is poisoned 0xAA before every call) ----
    k_init<<<(N + 255) / 256, 256, 0, stream>>>(deg, N);
    k_ve<<<1, 64, 0, stream>>>(We0, ae0, We1, ae1, ve);
    k_deg<<<(E + 255) / 256, 256, 0, stream>>>(dst, deg, E);
    k_scan1<<<SCAN_NBLK, SCAN_B, 0, stream>>>(deg, partial);
    k_scan2<<<1, SCAN_B, 0, stream>>>(partial);
    k_scan3<<<SCAN_NBLK, SCAN_B, 0, stream>>>(deg, partial, rp, cur);
    k_csr_fill<<<(E + 255) / 256, 256, 0, stream>>>(src, dst, eatt, ve, cur, pack, E);

    // ---- operand prep ----
    k_cvt_x<<<NPAD * 32 / 256, 256, 0, stream>>>(x, Ah, Al);
    k_cvt_w<128><<<(128 * 128 + 255) / 256, 256, 0, stream>>>(W0, Wth0, Wtl0);
    k_cvt_w<112><<<(128 * 112 + 255) / 256, 256, 0, stream>>>(W1, Wth1, Wtl1);

    // ---- layer 0: 128 -> 128 ----
    k_gemm_mfma<128><<<NPAD / 64, 256, 0, stream>>>(Ah, Al, Wth0, Wtl0, xs0b,
                                                    as0, ad0, als0, ald0);
    k_aggregate<128, 0><<<(N + 3) / 4, 256, 0, stream>>>(rp, pack, als0, ald0, xs0b, h);
    k_bn_stats1<128><<<BN_NBLK, 256, 0, stream>>>(h, psum, psq);
    k_bn_stats2<<<1, 1024, 0, stream>>>(psum, psq, sum0, sq0);

    // ---- layer 1: 128 -> 112 (BN0+ReLU fused into operand split) ----
    k_bn_cvt<<<NPAD * 32 / 256, 256, 0, stream>>>(h, Hh, Hl, sum0, sq0, bng, bnb);
    k_gemm_mfma<112><<<NPAD / 64, 256, 0, stream>>>(Hh, Hl, Wth1, Wtl1, xs1b,
                                                    as1, ad1, als1, ald1);
    k_aggregate<112, 1><<<(N + 3) / 4, 256, 0, stream>>>(rp, pack, als1, ald1, xs1b, out1);
    k_bn_stats1<112><<<BN_NBLK, 256, 0, stream>>>(out1, psum, psq);
    k_bn_stats2<<<1, 1024, 0, stream>>>(psum, psq, sum1, sq1);
    k_bn_apply<112><<<(N * 112 + 255) / 256, 256, 0, stream>>>(out1, (float*)d_out, sum1, sq1, bnfb ? bnfg : bnfg, bnfb, N);
}

// Round 8
// 439.053 us; speedup vs baseline: 6.9794x; 1.0970x over previous
//
#include <hip/hip_runtime.h>
#include <math.h>

// GAT 2-layer: N=50000 nodes, E=800000 edges, heads=1
// dims: 128 -> 128 (BN+ReLU) -> 112 (BN)
#define NN 50000
#define NPAD 50048               // 782 * 64, MFMA row tiles
#define NE 800000
#define SCAN_B 256
#define SCAN_NBLK ((NN + SCAN_B - 1) / SCAN_B)   // 196
#define BN_NBLK 256

struct EdgePack { int s; float a0, a1; };        // 12 B, one record per edge

typedef __attribute__((ext_vector_type(8))) short bf16x8;           // MFMA A/B frag
typedef __attribute__((ext_vector_type(4))) float f32x4;            // MFMA C/D frag
typedef __attribute__((ext_vector_type(8))) unsigned short u16x8;   // 16B gather

__device__ __forceinline__ unsigned short f2bf(float x) {
    unsigned u = __float_as_uint(x);
    u += 0x7fffu + ((u >> 16) & 1);              // round-to-nearest-even
    return (unsigned short)(u >> 16);
}
__device__ __forceinline__ float bf2f(unsigned short h) {
    return __uint_as_float(((unsigned)h) << 16);
}

// ---------------- init (deg zero) + ve (folded edge-attention weights) ----------------
// ve[0..7] = We0 @ a_edge0 ; ve[8..15] = We1 @ a_edge1   (heads=1 folding)
__global__ void k_init_ve(int* __restrict__ deg,
                          const float* __restrict__ We0, const float* __restrict__ ae0,
                          const float* __restrict__ We1, const float* __restrict__ ae1,
                          float* __restrict__ ve)
{
    int idx = blockIdx.x * blockDim.x + threadIdx.x;
    if (idx < NN) deg[idx] = 0;
    if (blockIdx.x == 0) {
        int j = threadIdx.x;
        if (j < 8) {
            float s = 0.f;
            for (int c = 0; c < 128; ++c) s += We0[j * 128 + c] * ae0[c];
            ve[j] = s;
        } else if (j < 16) {
            int jj = j - 8;
            float s = 0.f;
            for (int c = 0; c < 112; ++c) s += We1[jj * 112 + c] * ae1[c];
            ve[8 + jj] = s;
        }
    }
}

// ---------------- CSR build ----------------
__global__ void k_deg(const int* __restrict__ dst, int* __restrict__ deg, int E_)
{
    int e = blockIdx.x * blockDim.x + threadIdx.x;
    if (e < E_) atomicAdd(&deg[dst[e]], 1);
}

__global__ void k_scan1(const int* __restrict__ deg, int* __restrict__ partial)
{
    __shared__ int sm[SCAN_B];
    int t = threadIdx.x;
    int idx = blockIdx.x * SCAN_B + t;
    sm[t] = (idx < NN) ? deg[idx] : 0;
    __syncthreads();
    #pragma unroll
    for (int off = SCAN_B / 2; off > 0; off >>= 1) {
        if (t < off) sm[t] += sm[t + off];
        __syncthreads();
    }
    if (t == 0) partial[blockIdx.x] = sm[0];
}

// fused stage 2+3: each block computes its own prefix over partials, then local scan
__global__ void k_scan3(const int* __restrict__ deg, const int* __restrict__ partial,
                        int* __restrict__ rp, int* __restrict__ cur)
{
    __shared__ int sm[SCAN_B];
    __shared__ int pbase;
    int t = threadIdx.x;
    // prefix of block sums: sum partial[i] for i < blockIdx.x
    int pv = (t < SCAN_NBLK && t < blockIdx.x) ? partial[t] : 0;
    sm[t] = pv;
    __syncthreads();
    #pragma unroll
    for (int off = SCAN_B / 2; off > 0; off >>= 1) {
        if (t < off) sm[t] += sm[t + off];
        __syncthreads();
    }
    if (t == 0) pbase = sm[0];
    __syncthreads();
    // local inclusive scan of this block's 256 degrees
    int idx = blockIdx.x * SCAN_B + t;
    int v = (idx < NN) ? deg[idx] : 0;
    sm[t] = v;
    __syncthreads();
    #pragma unroll
    for (int off = 1; off < SCAN_B; off <<= 1) {
        int u = (t >= off) ? sm[t - off] : 0;
        __syncthreads();
        sm[t] += u;
        __syncthreads();
    }
    int excl = pbase + ((t == 0) ? 0 : sm[t - 1]);
    if (idx < NN) { rp[idx] = excl; cur[idx] = excl; }
    if (idx == NN - 1) rp[NN] = excl + v;
}

// ---------------- edge pack: per-edge attention dots for BOTH layers, CSR order ----------------
__global__ void k_csr_fill(const int* __restrict__ src, const int* __restrict__ dst,
                           const float* __restrict__ eatt, const float* __restrict__ ve,
                           int* __restrict__ cur, EdgePack* __restrict__ pack, int E_)
{
    int e = blockIdx.x * blockDim.x + threadIdx.x;
    if (e >= E_) return;
    const float4* ea = reinterpret_cast<const float4*>(eatt + (size_t)e * 8);
    float4 e0 = ea[0], e1 = ea[1];
    float a0 = e0.x * ve[0] + e0.y * ve[1] + e0.z * ve[2] + e0.w * ve[3]
             + e1.x * ve[4] + e1.y * ve[5] + e1.z * ve[6] + e1.w * ve[7];
    float a1 = e0.x * ve[8] + e0.y * ve[9] + e0.z * ve[10] + e0.w * ve[11]
             + e1.x * ve[12] + e1.y * ve[13] + e1.z * ve[14] + e1.w * ve[15];
    int d = dst[e];
    int pos = atomicAdd(&cur[d], 1);
    EdgePack p; p.s = src[e]; p.a0 = a0; p.a1 = a1;
    pack[pos] = p;
}

// ---------------- W [128][COLS] fp32 -> transposed split bf16 Wt[c][k], both layers ----------------
__global__ void k_cvt_w2(const float* __restrict__ W0, const float* __restrict__ W1,
                         unsigned short* __restrict__ Wth0, unsigned short* __restrict__ Wtl0,
                         unsigned short* __restrict__ Wth1, unsigned short* __restrict__ Wtl1)
{
    int idx = blockIdx.x * 256 + threadIdx.x;
    if (idx < 128 * 128) {
        int k = idx / 128, c = idx % 128;
        float v = W0[idx];
        unsigned short hi = f2bf(v);
        Wth0[c * 128 + k] = hi;
        Wtl0[c * 128 + k] = f2bf(v - bf2f(hi));
    } else if (idx < 128 * 128 + 128 * 112) {
        int i2 = idx - 128 * 128;
        int k = i2 / 112, c = i2 % 112;
        float v = W1[i2];
        unsigned short hi = f2bf(v);
        Wth1[c * 128 + k] = hi;
        Wtl1[c * 128 + k] = f2bf(v - bf2f(hi));
    }
}

// ---------------- MFMA GEMM: one wave = 16 rows x COLS, bf16x3 split precision ----------------
// Reads fp32 A directly (in-register split). BN_IN: BN+ReLU applied to A inline.
// out bf16 [NN][COLS]; als/ald = attention dots (full-K in wave -> direct store).
template<int COLS, bool BN_IN>
__global__ void k_gemm_mfma(const float* __restrict__ A,
                            const unsigned short* __restrict__ Wth,
                            const unsigned short* __restrict__ Wtl,
                            unsigned short* __restrict__ out,
                            const float* __restrict__ a_src, const float* __restrict__ a_dst,
                            float* __restrict__ als, float* __restrict__ ald,
                            const float* __restrict__ bsum, const float* __restrict__ bsq,
                            const float* __restrict__ gamma, const float* __restrict__ beta)
{
    constexpr int NT = COLS / 16;
    __shared__ float scN[128], shN[128];
    if (BN_IN) {
        if (threadIdx.x < 128) {
            int k = threadIdx.x;
            float invn = 1.0f / (float)NN;
            float mean = bsum[k] * invn;
            float var  = bsq[k] * invn - mean * mean;
            float sc = gamma[k] * rsqrtf(var + 1e-5f);
            scN[k] = sc;
            shN[k] = beta[k] - mean * sc;
        }
        __syncthreads();
    }
    int wv = threadIdx.x >> 6;
    int lane = threadIdx.x & 63;
    int r0 = blockIdx.x * 64 + wv * 16;
    int m = lane & 15;
    int quad = lane >> 4;
    int arow = r0 + m;
    int rc = (arow < NN) ? arow : NN - 1;    // clamp: pad rows computed but never stored
    const float* pa = A + (size_t)rc * 128 + quad * 8;

    f32x4 acc[NT];
    #pragma unroll
    for (int t = 0; t < NT; ++t) acc[t] = f32x4{0.f, 0.f, 0.f, 0.f};

    #pragma unroll
    for (int ks = 0; ks < 4; ++ks) {
        float4 v0 = *reinterpret_cast<const float4*>(pa + ks * 32);
        float4 v1 = *reinterpret_cast<const float4*>(pa + ks * 32 + 4);
        float vv[8] = {v0.x, v0.y, v0.z, v0.w, v1.x, v1.y, v1.z, v1.w};
        int kb = ks * 32 + quad * 8;
        bf16x8 ah, al;
        #pragma unroll
        for (int jj = 0; jj < 8; ++jj) {
            float f = vv[jj];
            if (BN_IN) f = fmaxf(f * scN[kb + jj] + shN[kb + jj], 0.f);
            unsigned short hi = f2bf(f);
            ah[jj] = (short)hi;
            al[jj] = (short)f2bf(f - bf2f(hi));
        }
        #pragma unroll
        for (int t = 0; t < NT; ++t) {
            size_t boff = (size_t)(t * 16 + m) * 128 + ks * 32 + quad * 8;
            bf16x8 bh = *reinterpret_cast<const bf16x8*>(Wth + boff);
            bf16x8 bl = *reinterpret_cast<const bf16x8*>(Wtl + boff);
            acc[t] = __builtin_amdgcn_mfma_f32_16x16x32_bf16(ah, bh, acc[t], 0, 0, 0);
            acc[t] = __builtin_amdgcn_mfma_f32_16x16x32_bf16(al, bh, acc[t], 0, 0, 0);
            acc[t] = __builtin_amdgcn_mfma_f32_16x16x32_bf16(ah, bl, acc[t], 0, 0, 0);
        }
    }

    // epilogue: bf16 store + fused attention dots (C/D: col=lane&15, row=quad*4+reg)
    float p[4] = {0.f, 0.f, 0.f, 0.f}, q[4] = {0.f, 0.f, 0.f, 0.f};
    #pragma unroll
    for (int t = 0; t < NT; ++t) {
        int c = t * 16 + m;
        float asv = a_src[c], adv = a_dst[c];
        #pragma unroll
        for (int rI = 0; rI < 4; ++rI) {
            float v = acc[t][rI];
            int row = r0 + quad * 4 + rI;
            if (row < NN) out[(size_t)row * COLS + c] = f2bf(v);
            p[rI] += v * asv;
            q[rI] += v * adv;
        }
    }
    #pragma unroll
    for (int rI = 0; rI < 4; ++rI) {
        #pragma unroll
        for (int off = 1; off <= 8; off <<= 1) {
            p[rI] += __shfl_xor(p[rI], off);
            q[rI] += __shfl_xor(q[rI], off);
        }
    }
    if (m == 0) {
        #pragma unroll
        for (int rI = 0; rI < 4; ++rI) {
            int row = r0 + quad * 4 + rI;
            if (row < NN) { als[row] = p[rI]; ald[row] = q[rI]; }
        }
    }
}

// ---------------- per-dst aggregate: one wave per node, quarter-wave edge split ----------------
// 16 lanes per edge, ushort8 (16B) per lane; 4 edges/pass, unroll x2 -> 8 gathers in flight.
template<int COLS, int LAYER>
__global__ void k_aggregate(const int* __restrict__ rp, const EdgePack* __restrict__ pack,
                            const float* __restrict__ als, const float* __restrict__ ald,
                            const unsigned short* __restrict__ xs, float* __restrict__ out)
{
    int w = blockIdx.x * 4 + (threadIdx.x >> 6);
    int lane = threadIdx.x & 63;
    if (w >= NN) return;
    int beg = rp[w], end = rp[w + 1];
    float aldv = ald[w];
    int q = lane >> 4;               // quarter 0..3 -> edge slot
    int ql = lane & 15;
    int col = ql * 8;
    bool act = (col < COLS);

    float acc[8] = {0.f, 0.f, 0.f, 0.f, 0.f, 0.f, 0.f, 0.f};
    float den = 0.f;
    int j = beg;
    for (; j + 8 <= end; j += 8) {
        EdgePack p0 = pack[j + q];
        EdgePack p1 = pack[j + 4 + q];
        float a0 = als[p0.s] + aldv + (LAYER ? p0.a1 : p0.a0);
        float a1 = als[p1.s] + aldv + (LAYER ? p1.a1 : p1.a0);
        a0 = a0 > 0.f ? a0 : 0.2f * a0;
        a1 = a1 > 0.f ? a1 : 0.2f * a1;
        float ex0 = __expf(a0), ex1 = __expf(a1);
        den += ex0 + ex1;
        if (act) {
            u16x8 u0 = *reinterpret_cast<const u16x8*>(xs + (size_t)p0.s * COLS + col);
            u16x8 u1 = *reinterpret_cast<const u16x8*>(xs + (size_t)p1.s * COLS + col);
            #pragma unroll
            for (int k = 0; k < 8; ++k)
                acc[k] += ex0 * bf2f(u0[k]) + ex1 * bf2f(u1[k]);
        }
    }
    for (; j < end; j += 4) {
        int jj = j + q;
        if (jj < end) {
            EdgePack p = pack[jj];
            float a = als[p.s] + aldv + (LAYER ? p.a1 : p.a0);
            a = a > 0.f ? a : 0.2f * a;
            float ex = __expf(a);
            den += ex;
            if (act) {
                u16x8 u = *reinterpret_cast<const u16x8*>(xs + (size_t)p.s * COLS + col);
                #pragma unroll
                for (int k = 0; k < 8; ++k)
                    acc[k] += ex * bf2f(u[k]);
            }
        }
    }
    // fold the four quarters (lane L, L^16, L^32, L^48 hold the same columns)
    #pragma unroll
    for (int k = 0; k < 8; ++k) {
        acc[k] += __shfl_xor(acc[k], 16);
        acc[k] += __shfl_xor(acc[k], 32);
    }
    den += __shfl_xor(den, 16);
    den += __shfl_xor(den, 32);
    float inv = (end > beg) ? 1.f / den : 0.f;
    if (q == 0 && act) {
        float4 o0, o1;
        o0.x = acc[0] * inv; o0.y = acc[1] * inv; o0.z = acc[2] * inv; o0.w = acc[3] * inv;
        o1.x = acc[4] * inv; o1.y = acc[5] * inv; o1.z = acc[6] * inv; o1.w = acc[7] * inv;
        *reinterpret_cast<float4*>(out + (size_t)w * COLS + col) = o0;
        *reinterpret_cast<float4*>(out + (size_t)w * COLS + col + 4) = o1;
    }
}

// ---------------- batchnorm stats, stage 1: per-block partials (no atomics) ----------------
template<int COLS>
__global__ void k_bn_stats1(const float* __restrict__ h, float* __restrict__ psum,
                            float* __restrict__ psq)
{
    __shared__ float sm[256], sq[256];
    int t = threadIdx.x;
    int c = t & 127;
    int g = t >> 7;
    float s = 0.f, q = 0.f;
    if (c < COLS) {
        for (int r = blockIdx.x * 2 + g; r < NN; r += BN_NBLK * 2) {
            float v = h[(size_t)r * COLS + c];
            s += v; q += v * v;
        }
    }
    sm[t] = s; sq[t] = q;
    __syncthreads();
    if (t < 128) {
        psum[blockIdx.x * 128 + t] = sm[t] + sm[t + 128];
        psq [blockIdx.x * 128 + t] = sq[t] + sq[t + 128];
    }
}

// stage 2: one block reduces BN_NBLK partials per channel
__global__ void k_bn_stats2(const float* __restrict__ psum, const float* __restrict__ psq,
                            float* __restrict__ sums, float* __restrict__ sqs)
{
    __shared__ float sm[1024], sq[1024];
    int t = threadIdx.x;
    int c = t & 127;
    int g = t >> 7;          // 0..7
    float s = 0.f, q = 0.f;
    for (int b = g; b < BN_NBLK; b += 8) {
        s += psum[b * 128 + c];
        q += psq [b * 128 + c];
    }
    sm[t] = s; sq[t] = q;
    __syncthreads();
    #pragma unroll
    for (int off = 512; off >= 128; off >>= 1) {
        if (t < off) { sm[t] += sm[t + off]; sq[t] += sq[t + off]; }
        __syncthreads();
    }
    if (t < 128) { sums[t] = sm[t]; sqs[t] = sq[t]; }
}

// ---------------- batchnorm apply (final layer -> d_out) ----------------
template<int COLS>
__global__ void k_bn_apply(const float* __restrict__ in, float* __restrict__ out,
                           const float* __restrict__ sums, const float* __restrict__ sqs,
                           const float* __restrict__ gamma, const float* __restrict__ beta,
                           int n)
{
    int idx = blockIdx.x * blockDim.x + threadIdx.x;
    if (idx >= n * COLS) return;
    int c = idx % COLS;
    float invn = 1.0f / (float)n;
    float mean = sums[c] * invn;
    float var  = sqs[c] * invn - mean * mean;     // biased, matches jnp var
    float sc = gamma[c] * rsqrtf(var + 1e-5f);
    float sh = beta[c] - mean * sc;
    out[idx] = in[idx] * sc + sh;
}

extern "C" void kernel_launch(void* const* d_in, const int* in_sizes, int n_in,
                              void* d_out, int out_size, void* d_ws, size_t ws_size,
                              hipStream_t stream)
{
    const float* x    = (const float*)d_in[0];
    const int*   eidx = (const int*)d_in[1];
    const float* eatt = (const float*)d_in[2];
    const float* W0   = (const float*)d_in[3];
    const float* as0  = (const float*)d_in[4];
    const float* ad0  = (const float*)d_in[5];
    const float* We0  = (const float*)d_in[6];
    const float* ae0  = (const float*)d_in[7];
    // d_in[8] = b0 : cancels through BN
    const float* W1   = (const float*)d_in[9];
    const float* as1  = (const float*)d_in[10];
    const float* ad1  = (const float*)d_in[11];
    const float* We1  = (const float*)d_in[12];
    const float* ae1  = (const float*)d_in[13];
    // d_in[14] = b1 : cancels through BN
    const float* bng  = (const float*)d_in[15];
    const float* bnb  = (const float*)d_in[16];
    const float* bnfg = (const float*)d_in[17];
    const float* bnfb = (const float*)d_in[18];

    const int N = NN, E = NE;
    const int* src = eidx;
    const int* dst = eidx + E;

    float* ws = (float*)d_ws;
    size_t off = 0;
    unsigned short* xs0b = (unsigned short*)(ws + off); off += (size_t)N * 64;   // N*128 bf16
    float* h   = ws + off;      off += (size_t)N * 128;                          // fp32; out1 aliases
    unsigned short* xs1b = (unsigned short*)(ws + off); off += (size_t)N * 56;   // N*112 bf16
    EdgePack* pack = (EdgePack*)(ws + off);             off += (size_t)E * 3;
    int*   rp   = (int*)(ws + off);     off += N + 2;
    int*   cur  = (int*)(ws + off);     off += N;
    int*   deg  = (int*)(ws + off);     off += N;
    float* als0 = ws + off;     off += N;
    float* ald0 = ws + off;     off += N;
    float* als1 = ws + off;     off += N;
    float* ald1 = ws + off;     off += N;
    float* stats = ws + off;    off += 512;
    float* ve = ws + off;       off += 16;
    int*   partial = (int*)(ws + off);  off += SCAN_NBLK;
    float* psum = ws + off;     off += BN_NBLK * 128;
    float* psq  = ws + off;     off += BN_NBLK * 128;
    unsigned short* Wth0 = (unsigned short*)(ws + off); off += 128 * 64;         // 128x128 bf16
    unsigned short* Wtl0 = (unsigned short*)(ws + off); off += 128 * 64;
    unsigned short* Wth1 = (unsigned short*)(ws + off); off += 112 * 64;         // 112x128 bf16
    unsigned short* Wtl1 = (unsigned short*)(ws + off); off += 112 * 64;
    float* out1 = h;            // alias: h (fp32) dead after layer-1 gemm consumes it

    float* sum0 = stats;
    float* sq0  = stats + 128;
    float* sum1 = stats + 256;
    float* sq1  = stats + 384;

    // ---- init + CSR structure (ws is poisoned 0xAA before every call) ----
    k_init_ve<<<(N + 255) / 256, 256, 0, stream>>>(deg, We0, ae0, We1, ae1, ve);
    k_deg<<<(E + 255) / 256, 256, 0, stream>>>(dst, deg, E);
    k_scan1<<<SCAN_NBLK, SCAN_B, 0, stream>>>(deg, partial);
    k_scan3<<<SCAN_NBLK, SCAN_B, 0, stream>>>(deg, partial, rp, cur);
    k_csr_fill<<<(E + 255) / 256, 256, 0, stream>>>(src, dst, eatt, ve, cur, pack, E);
    k_cvt_w2<<<(128 * 128 + 128 * 112 + 255) / 256, 256, 0, stream>>>(W0, W1, Wth0, Wtl0, Wth1, Wtl1);

    // ---- layer 0: 128 -> 128 ----
    k_gemm_mfma<128, false><<<NPAD / 64, 256, 0, stream>>>(x, Wth0, Wtl0, xs0b,
                                                           as0, ad0, als0, ald0,
                                                           nullptr, nullptr, nullptr, nullptr);
    k_aggregate<128, 0><<<(N + 3) / 4, 256, 0, stream>>>(rp, pack, als0, ald0, xs0b, h);
    k_bn_stats1<128><<<BN_NBLK, 256, 0, stream>>>(h, psum, psq);
    k_bn_stats2<<<1, 1024, 0, stream>>>(psum, psq, sum0, sq0);

    // ---- layer 1: 128 -> 112 (BN0+ReLU fused into GEMM A-load) ----
    k_gemm_mfma<112, true><<<NPAD / 64, 256, 0, stream>>>(h, Wth1, Wtl1, xs1b,
                                                          as1, ad1, als1, ald1,
                                                          sum0, sq0, bng, bnb);
    k_aggregate<112, 1><<<(N + 3) / 4, 256, 0, stream>>>(rp, pack, als1, ald1, xs1b, out1);
    k_bn_stats1<112><<<BN_NBLK, 256, 0, stream>>>(out1, psum, psq);
    k_bn_stats2<<<1, 1024, 0, stream>>>(psum, psq, sum1, sq1);
    k_bn_apply<112><<<(N * 112 + 255) / 256, 256, 0, stream>>>(out1, (float*)d_out, sum1, sq1, bnfg, bnfb, N);
}

// Round 9
// 401.348 us; speedup vs baseline: 7.6351x; 1.0939x over previous
//
#include <hip/hip_runtime.h>
#include <math.h>

// GAT 2-layer: N=50000 nodes, E=800000 edges, heads=1
// dims: 128 -> 128 (BN+ReLU) -> 112 (BN)
#define NN 50000
#define NPAD 50048               // 782 * 64, MFMA row tiles
#define NE 800000
#define SCAN_B 256
#define SCAN_NBLK ((NN + SCAN_B - 1) / SCAN_B)   // 196
#define CSR_NBLK ((NE + 255) / 256)              // 3125
#define GEMM0_NBLK (NPAD / 64)                   // 782
#define AGG_NBLK 2048                            // = resident-block capacity (256thr, low VGPR)

typedef __attribute__((ext_vector_type(8))) short bf16x8;           // MFMA A/B frag
typedef __attribute__((ext_vector_type(4))) float f32x4;            // MFMA C/D frag
typedef __attribute__((ext_vector_type(8))) unsigned short u16x8;   // 16B gather

__device__ __forceinline__ unsigned short f2bf(float x) {
    unsigned u = __float_as_uint(x);
    u += 0x7fffu + ((u >> 16) & 1);              // round-to-nearest-even
    return (unsigned short)(u >> 16);
}
__device__ __forceinline__ float bf2f(unsigned short h) {
    return __uint_as_float(((unsigned)h) << 16);
}

// ---------------- init: deg/stats zero + ve fold + W split-transpose ----------------
// ve[0..7] = We0 @ a_edge0 ; ve[8..15] = We1 @ a_edge1   (heads=1 folding)
__global__ void k_init_cvt(int* __restrict__ deg, float* __restrict__ stats,
                           const float* __restrict__ We0, const float* __restrict__ ae0,
                           const float* __restrict__ We1, const float* __restrict__ ae1,
                           float* __restrict__ ve,
                           const float* __restrict__ W0, const float* __restrict__ W1,
                           unsigned short* __restrict__ Wth0, unsigned short* __restrict__ Wtl0,
                           unsigned short* __restrict__ Wth1, unsigned short* __restrict__ Wtl1)
{
    int idx = blockIdx.x * 256 + threadIdx.x;
    if (idx < NN) deg[idx] = 0;
    if (idx < 512) stats[idx] = 0.f;
    if (idx < 128 * 128) {
        int k = idx / 128, c = idx % 128;
        float v = W0[idx];
        unsigned short hi = f2bf(v);
        Wth0[c * 128 + k] = hi;
        Wtl0[c * 128 + k] = f2bf(v - bf2f(hi));
    } else if (idx < 128 * 128 + 128 * 112) {
        int i2 = idx - 128 * 128;
        int k = i2 / 112, c = i2 % 112;
        float v = W1[i2];
        unsigned short hi = f2bf(v);
        Wth1[c * 128 + k] = hi;
        Wtl1[c * 128 + k] = f2bf(v - bf2f(hi));
    }
    if (blockIdx.x == gridDim.x - 1) {
        int j = threadIdx.x;
        if (j < 8) {
            float s = 0.f;
            for (int c = 0; c < 128; ++c) s += We0[j * 128 + c] * ae0[c];
            ve[j] = s;
        } else if (j < 16) {
            int jj = j - 8;
            float s = 0.f;
            for (int c = 0; c < 112; ++c) s += We1[jj * 112 + c] * ae1[c];
            ve[8 + jj] = s;
        }
    }
}

// ---------------- CSR build ----------------
__global__ void k_deg(const int* __restrict__ dst, int* __restrict__ deg, int E_)
{
    int e = blockIdx.x * blockDim.x + threadIdx.x;
    if (e < E_) atomicAdd(&deg[dst[e]], 1);
}

__global__ void k_scan1(const int* __restrict__ deg, int* __restrict__ partial)
{
    __shared__ int sm[SCAN_B];
    int t = threadIdx.x;
    int idx = blockIdx.x * SCAN_B + t;
    sm[t] = (idx < NN) ? deg[idx] : 0;
    __syncthreads();
    #pragma unroll
    for (int off = SCAN_B / 2; off > 0; off >>= 1) {
        if (t < off) sm[t] += sm[t + off];
        __syncthreads();
    }
    if (t == 0) partial[blockIdx.x] = sm[0];
}

// fused stage 2+3: each block computes its own prefix over partials, then local scan
__global__ void k_scan3(const int* __restrict__ deg, const int* __restrict__ partial,
                        int* __restrict__ rp, int* __restrict__ cur)
{
    __shared__ int sm[SCAN_B];
    __shared__ int pbase;
    int t = threadIdx.x;
    int pv = (t < SCAN_NBLK && t < blockIdx.x) ? partial[t] : 0;
    sm[t] = pv;
    __syncthreads();
    #pragma unroll
    for (int off = SCAN_B / 2; off > 0; off >>= 1) {
        if (t < off) sm[t] += sm[t + off];
        __syncthreads();
    }
    if (t == 0) pbase = sm[0];
    __syncthreads();
    int idx = blockIdx.x * SCAN_B + t;
    int v = (idx < NN) ? deg[idx] : 0;
    sm[t] = v;
    __syncthreads();
    #pragma unroll
    for (int off = 1; off < SCAN_B; off <<= 1) {
        int u = (t >= off) ? sm[t - off] : 0;
        __syncthreads();
        sm[t] += u;
        __syncthreads();
    }
    int excl = pbase + ((t == 0) ? 0 : sm[t - 1]);
    if (idx < NN) { rp[idx] = excl; cur[idx] = excl; }
    if (idx == NN - 1) rp[NN] = excl + v;
}

// ---------------- MFMA GEMM body: one wave = 16 rows x COLS, bf16x3 split precision ----------------
template<int COLS, bool BN_IN>
__device__ __forceinline__ void gemm_body(int bid, const float* __restrict__ A,
                            const unsigned short* __restrict__ Wth,
                            const unsigned short* __restrict__ Wtl,
                            unsigned short* __restrict__ out,
                            const float* __restrict__ a_src, const float* __restrict__ a_dst,
                            float* __restrict__ als, float* __restrict__ ald,
                            const float* __restrict__ bsum, const float* __restrict__ bsq,
                            const float* __restrict__ gamma, const float* __restrict__ beta)
{
    constexpr int NT = COLS / 16;
    __shared__ float scN[128], shN[128];
    if (BN_IN) {
        if (threadIdx.x < 128) {
            int k = threadIdx.x;
            float invn = 1.0f / (float)NN;
            float mean = bsum[k] * invn;
            float var  = bsq[k] * invn - mean * mean;
            float sc = gamma[k] * rsqrtf(var + 1e-5f);
            scN[k] = sc;
            shN[k] = beta[k] - mean * sc;
        }
        __syncthreads();
    }
    int wv = threadIdx.x >> 6;
    int lane = threadIdx.x & 63;
    int r0 = bid * 64 + wv * 16;
    int m = lane & 15;
    int quad = lane >> 4;
    int arow = r0 + m;
    int rc = (arow < NN) ? arow : NN - 1;    // clamp: pad rows computed but never stored
    const float* pa = A + (size_t)rc * 128 + quad * 8;

    f32x4 acc[NT];
    #pragma unroll
    for (int t = 0; t < NT; ++t) acc[t] = f32x4{0.f, 0.f, 0.f, 0.f};

    #pragma unroll
    for (int ks = 0; ks < 4; ++ks) {
        float4 v0 = *reinterpret_cast<const float4*>(pa + ks * 32);
        float4 v1 = *reinterpret_cast<const float4*>(pa + ks * 32 + 4);
        float vv[8] = {v0.x, v0.y, v0.z, v0.w, v1.x, v1.y, v1.z, v1.w};
        int kb = ks * 32 + quad * 8;
        bf16x8 ah, al;
        #pragma unroll
        for (int jj = 0; jj < 8; ++jj) {
            float f = vv[jj];
            if (BN_IN) f = fmaxf(f * scN[kb + jj] + shN[kb + jj], 0.f);
            unsigned short hi = f2bf(f);
            ah[jj] = (short)hi;
            al[jj] = (short)f2bf(f - bf2f(hi));
        }
        #pragma unroll
        for (int t = 0; t < NT; ++t) {
            size_t boff = (size_t)(t * 16 + m) * 128 + ks * 32 + quad * 8;
            bf16x8 bh = *reinterpret_cast<const bf16x8*>(Wth + boff);
            bf16x8 bl = *reinterpret_cast<const bf16x8*>(Wtl + boff);
            acc[t] = __builtin_amdgcn_mfma_f32_16x16x32_bf16(ah, bh, acc[t], 0, 0, 0);
            acc[t] = __builtin_amdgcn_mfma_f32_16x16x32_bf16(al, bh, acc[t], 0, 0, 0);
            acc[t] = __builtin_amdgcn_mfma_f32_16x16x32_bf16(ah, bl, acc[t], 0, 0, 0);
        }
    }

    // epilogue: bf16 store + fused attention dots (C/D: col=lane&15, row=quad*4+reg)
    float p[4] = {0.f, 0.f, 0.f, 0.f}, q[4] = {0.f, 0.f, 0.f, 0.f};
    #pragma unroll
    for (int t = 0; t < NT; ++t) {
        int c = t * 16 + m;
        float asv = a_src[c], adv = a_dst[c];
        #pragma unroll
        for (int rI = 0; rI < 4; ++rI) {
            float v = acc[t][rI];
            int row = r0 + quad * 4 + rI;
            if (row < NN) out[(size_t)row * COLS + c] = f2bf(v);
            p[rI] += v * asv;
            q[rI] += v * adv;
        }
    }
    #pragma unroll
    for (int rI = 0; rI < 4; ++rI) {
        #pragma unroll
        for (int off = 1; off <= 8; off <<= 1) {
            p[rI] += __shfl_xor(p[rI], off);
            q[rI] += __shfl_xor(q[rI], off);
        }
    }
    if (m == 0) {
        #pragma unroll
        for (int rI = 0; rI < 4; ++rI) {
            int row = r0 + quad * 4 + rI;
            if (row < NN) { als[row] = p[rI]; ald[row] = q[rI]; }
        }
    }
}

// ---------------- fused: csr_fill (long pole, blocks first) + layer-0 GEMM ----------------
__global__ void k_fused0(const int* __restrict__ src, const int* __restrict__ dst,
                         const float* __restrict__ eatt, const float* __restrict__ ve,
                         int* __restrict__ cur, int4* __restrict__ pack,
                         const float* __restrict__ x,
                         const unsigned short* __restrict__ Wth0,
                         const unsigned short* __restrict__ Wtl0,
                         unsigned short* __restrict__ xs0b,
                         const float* __restrict__ as0, const float* __restrict__ ad0,
                         float* __restrict__ als0, float* __restrict__ ald0)
{
    if (blockIdx.x < CSR_NBLK) {
        int e = blockIdx.x * 256 + threadIdx.x;
        if (e >= NE) return;
        const float4* ea = reinterpret_cast<const float4*>(eatt + (size_t)e * 8);
        float4 e0 = ea[0], e1 = ea[1];
        float a0 = e0.x * ve[0] + e0.y * ve[1] + e0.z * ve[2] + e0.w * ve[3]
                 + e1.x * ve[4] + e1.y * ve[5] + e1.z * ve[6] + e1.w * ve[7];
        float a1 = e0.x * ve[8] + e0.y * ve[9] + e0.z * ve[10] + e0.w * ve[11]
                 + e1.x * ve[12] + e1.y * ve[13] + e1.z * ve[14] + e1.w * ve[15];
        int d = dst[e];
        int pos = atomicAdd(&cur[d], 1);
        int4 rec;
        rec.x = src[e];
        rec.y = __float_as_int(a0);
        rec.z = __float_as_int(a1);
        rec.w = 0;
        pack[pos] = rec;
    } else {
        gemm_body<128, false>(blockIdx.x - CSR_NBLK, x, Wth0, Wtl0, xs0b, as0, ad0,
                              als0, ald0, nullptr, nullptr, nullptr, nullptr);
    }
}

// ---------------- standalone layer-1 GEMM (BN+ReLU fused into A-load) ----------------
template<int COLS, bool BN_IN>
__global__ void k_gemm_mfma(const float* __restrict__ A,
                            const unsigned short* __restrict__ Wth,
                            const unsigned short* __restrict__ Wtl,
                            unsigned short* __restrict__ out,
                            const float* __restrict__ a_src, const float* __restrict__ a_dst,
                            float* __restrict__ als, float* __restrict__ ald,
                            const float* __restrict__ bsum, const float* __restrict__ bsq,
                            const float* __restrict__ gamma, const float* __restrict__ beta)
{
    gemm_body<COLS, BN_IN>(blockIdx.x, A, Wth, Wtl, out, a_src, a_dst, als, ald,
                           bsum, bsq, gamma, beta);
}

// ---------------- per-dst aggregate: grid-stride, quarter-wave edge split, fused BN partials --
// 16 lanes per edge, u16x8 (16B) per lane; 4 edges/pass, unroll x2 -> 8 gathers in flight.
template<int COLS, int LAYER>
__global__ void k_aggregate(const int* __restrict__ rp, const int4* __restrict__ pack,
                            const float* __restrict__ als, const float* __restrict__ ald,
                            const unsigned short* __restrict__ xs, float* __restrict__ out,
                            float* __restrict__ psum, float* __restrict__ psq)
{
    __shared__ float sS[4 * 128], sQ[4 * 128];
    int wv = threadIdx.x >> 6;
    int lane = threadIdx.x & 63;
    int q = lane >> 4;               // quarter 0..3 -> edge slot
    int ql = lane & 15;
    int col = ql * 8;
    bool act = (col < COLS);
    float bs[8] = {0.f,0.f,0.f,0.f,0.f,0.f,0.f,0.f};
    float bq[8] = {0.f,0.f,0.f,0.f,0.f,0.f,0.f,0.f};

    for (int w = blockIdx.x * 4 + wv; w < NN; w += AGG_NBLK * 4) {
        int beg = rp[w], end = rp[w + 1];
        float aldv = ald[w];
        float acc[8] = {0.f,0.f,0.f,0.f,0.f,0.f,0.f,0.f};
        float den = 0.f;
        int j = beg;
        for (; j + 8 <= end; j += 8) {
            int4 r0 = pack[j + q];
            int4 r1 = pack[j + 4 + q];
            float a0 = als[r0.x] + aldv + __int_as_float(LAYER ? r0.z : r0.y);
            float a1 = als[r1.x] + aldv + __int_as_float(LAYER ? r1.z : r1.y);
            a0 = a0 > 0.f ? a0 : 0.2f * a0;
            a1 = a1 > 0.f ? a1 : 0.2f * a1;
            float ex0 = __expf(a0), ex1 = __expf(a1);
            den += ex0 + ex1;
            if (act) {
                u16x8 u0 = *reinterpret_cast<const u16x8*>(xs + (size_t)r0.x * COLS + col);
                u16x8 u1 = *reinterpret_cast<const u16x8*>(xs + (size_t)r1.x * COLS + col);
                #pragma unroll
                for (int k = 0; k < 8; ++k)
                    acc[k] += ex0 * bf2f(u0[k]) + ex1 * bf2f(u1[k]);
            }
        }
        for (; j < end; j += 4) {
            int jj = j + q;
            if (jj < end) {
                int4 r = pack[jj];
                float a = als[r.x] + aldv + __int_as_float(LAYER ? r.z : r.y);
                a = a > 0.f ? a : 0.2f * a;
                float ex = __expf(a);
                den += ex;
                if (act) {
                    u16x8 u = *reinterpret_cast<const u16x8*>(xs + (size_t)r.x * COLS + col);
                    #pragma unroll
                    for (int k = 0; k < 8; ++k)
                        acc[k] += ex * bf2f(u[k]);
                }
            }
        }
        #pragma unroll
        for (int k = 0; k < 8; ++k) {
            acc[k] += __shfl_xor(acc[k], 16);
            acc[k] += __shfl_xor(acc[k], 32);
        }
        den += __shfl_xor(den, 16);
        den += __shfl_xor(den, 32);
        float inv = (end > beg) ? 1.f / den : 0.f;
        if (q == 0 && act) {
            float o[8];
            #pragma unroll
            for (int k = 0; k < 8; ++k) {
                o[k] = acc[k] * inv;
                bs[k] += o[k];
                bq[k] += o[k] * o[k];
            }
            float4 o0, o1;
            o0.x = o[0]; o0.y = o[1]; o0.z = o[2]; o0.w = o[3];
            o1.x = o[4]; o1.y = o[5]; o1.z = o[6]; o1.w = o[7];
            *reinterpret_cast<float4*>(out + (size_t)w * COLS + col) = o0;
            *reinterpret_cast<float4*>(out + (size_t)w * COLS + col + 4) = o1;
        }
    }
    // fold BN partials across the block's 4 waves
    if (q == 0) {
        #pragma unroll
        for (int k = 0; k < 8; ++k) {
            sS[wv * 128 + col + k] = bs[k];
            sQ[wv * 128 + col + k] = bq[k];
        }
    }
    __syncthreads();
    int t = threadIdx.x;
    if (t < 128) {
        psum[(size_t)blockIdx.x * 128 + t] = sS[t] + sS[128 + t] + sS[256 + t] + sS[384 + t];
        psq [(size_t)blockIdx.x * 128 + t] = sQ[t] + sQ[128 + t] + sQ[256 + t] + sQ[384 + t];
    }
}

// ---------------- BN stats stage 2: reduce AGG_NBLK partials (lightly-contended atomics) ----
__global__ void k_bn_stats2(const float* __restrict__ psum, const float* __restrict__ psq,
                            float* __restrict__ sums, float* __restrict__ sqs)
{
    int t = threadIdx.x;
    int c = t & 127;
    constexpr int ROWS = AGG_NBLK / 128;    // 16
    const float* sp = (t < 128) ? psum : psq;
    float s = 0.f;
    #pragma unroll 4
    for (int i = 0; i < ROWS; ++i)
        s += sp[(size_t)(blockIdx.x * ROWS + i) * 128 + c];
    unsafeAtomicAdd(((t < 128) ? sums : sqs) + c, s);
}

// ---------------- batchnorm apply (final layer -> d_out) ----------------
template<int COLS>
__global__ void k_bn_apply(const float* __restrict__ in, float* __restrict__ out,
                           const float* __restrict__ sums, const float* __restrict__ sqs,
                           const float* __restrict__ gamma, const float* __restrict__ beta,
                           int n)
{
    int idx = blockIdx.x * blockDim.x + threadIdx.x;
    if (idx >= n * COLS) return;
    int c = idx % COLS;
    float invn = 1.0f / (float)n;
    float mean = sums[c] * invn;
    float var  = sqs[c] * invn - mean * mean;     // biased, matches jnp var
    float sc = gamma[c] * rsqrtf(var + 1e-5f);
    float sh = beta[c] - mean * sc;
    out[idx] = in[idx] * sc + sh;
}

extern "C" void kernel_launch(void* const* d_in, const int* in_sizes, int n_in,
                              void* d_out, int out_size, void* d_ws, size_t ws_size,
                              hipStream_t stream)
{
    const float* x    = (const float*)d_in[0];
    const int*   eidx = (const int*)d_in[1];
    const float* eatt = (const float*)d_in[2];
    const float* W0   = (const float*)d_in[3];
    const float* as0  = (const float*)d_in[4];
    const float* ad0  = (const float*)d_in[5];
    const float* We0  = (const float*)d_in[6];
    const float* ae0  = (const float*)d_in[7];
    // d_in[8] = b0 : cancels through BN
    const float* W1   = (const float*)d_in[9];
    const float* as1  = (const float*)d_in[10];
    const float* ad1  = (const float*)d_in[11];
    const float* We1  = (const float*)d_in[12];
    const float* ae1  = (const float*)d_in[13];
    // d_in[14] = b1 : cancels through BN
    const float* bng  = (const float*)d_in[15];
    const float* bnb  = (const float*)d_in[16];
    const float* bnfg = (const float*)d_in[17];
    const float* bnfb = (const float*)d_in[18];

    const int N = NN, E = NE;
    const int* src = eidx;
    const int* dst = eidx + E;

    float* ws = (float*)d_ws;
    size_t off = 0;
    unsigned short* xs0b = (unsigned short*)(ws + off); off += (size_t)N * 64;   // N*128 bf16
    float* h   = ws + off;      off += (size_t)N * 128;                          // fp32; out1 aliases
    unsigned short* xs1b = (unsigned short*)(ws + off); off += (size_t)N * 56;   // N*112 bf16
    int4*  pack = (int4*)(ws + off);    off += (size_t)E * 4;                    // 16B/edge, aligned
    int*   rp   = (int*)(ws + off);     off += N + 2;
    int*   cur  = (int*)(ws + off);     off += N;
    int*   deg  = (int*)(ws + off);     off += N;
    float* als0 = ws + off;     off += N;
    float* ald0 = ws + off;     off += N;
    float* als1 = ws + off;     off += N;
    float* ald1 = ws + off;     off += N;
    float* stats = ws + off;    off += 512;
    float* ve = ws + off;       off += 16;
    int*   partial = (int*)(ws + off);  off += SCAN_NBLK;
    float* psum = ws + off;     off += (size_t)AGG_NBLK * 128;
    float* psq  = ws + off;     off += (size_t)AGG_NBLK * 128;
    unsigned short* Wth0 = (unsigned short*)(ws + off); off += 128 * 64;         // 128x128 bf16
    unsigned short* Wtl0 = (unsigned short*)(ws + off); off += 128 * 64;
    unsigned short* Wth1 = (unsigned short*)(ws + off); off += 112 * 64;         // 112x128 bf16
    unsigned short* Wtl1 = (unsigned short*)(ws + off); off += 112 * 64;
    float* out1 = h;            // alias: h (fp32) dead after layer-1 gemm consumes it

    float* sum0 = stats;
    float* sq0  = stats + 128;
    float* sum1 = stats + 256;
    float* sq1  = stats + 384;

    // ---- init + CSR structure (ws is poisoned 0xAA before every call) ----
    k_init_cvt<<<(N + 255) / 256, 256, 0, stream>>>(deg, stats, We0, ae0, We1, ae1, ve,
                                                    W0, W1, Wth0, Wtl0, Wth1, Wtl1);
    k_deg<<<CSR_NBLK, 256, 0, stream>>>(dst, deg, E);
    k_scan1<<<SCAN_NBLK, SCAN_B, 0, stream>>>(deg, partial);
    k_scan3<<<SCAN_NBLK, SCAN_B, 0, stream>>>(deg, partial, rp, cur);

    // ---- fused: CSR scatter-fill (long pole) || layer-0 GEMM ----
    k_fused0<<<CSR_NBLK + GEMM0_NBLK, 256, 0, stream>>>(src, dst, eatt, ve, cur, pack,
                                                        x, Wth0, Wtl0, xs0b, as0, ad0,
                                                        als0, ald0);

    // ---- layer 0 aggregate (+BN partials) ----
    k_aggregate<128, 0><<<AGG_NBLK, 256, 0, stream>>>(rp, pack, als0, ald0, xs0b, h, psum, psq);
    k_bn_stats2<<<128, 256, 0, stream>>>(psum, psq, sum0, sq0);

    // ---- layer 1: 128 -> 112 (BN0+ReLU fused into GEMM A-load) ----
    k_gemm_mfma<112, true><<<GEMM0_NBLK, 256, 0, stream>>>(h, Wth1, Wtl1, xs1b,
                                                           as1, ad1, als1, ald1,
                                                           sum0, sq0, bng, bnb);
    k_aggregate<112, 1><<<AGG_NBLK, 256, 0, stream>>>(rp, pack, als1, ald1, xs1b, out1, psum, psq);
    k_bn_stats2<<<128, 256, 0, stream>>>(psum, psq, sum1, sq1);
    k_bn_apply<112><<<(N * 112 + 255) / 256, 256, 0, stream>>>(out1, (float*)d_out, sum1, sq1, bnfg, bnfb, N);
}